// Round 1
// baseline (2663.769 us; speedup 1.0000x reference)
//
#include <hip/hip_runtime.h>
#include <math.h>

#define B_ 8
#define C_ 512
#define S_ 1024
#define HD 64
#define NHEADS 8
#define NGROUPS 8
#define DT_STEP 0.1f
#define EPS_GN 1e-5f

// ---------------- GroupNorm: x[B,C,S] -> h[B,C,S] ----------------
__global__ __launch_bounds__(256) void groupnorm_kernel(
    const float* __restrict__ x, const float* __restrict__ scale,
    const float* __restrict__ bias, float* __restrict__ h) {
  int bg = blockIdx.x;                 // B*NGROUPS = 64
  int b = bg / NGROUPS, g = bg % NGROUPS;
  const int CPG = C_ / NGROUPS;        // 64
  const int GS = CPG * S_;             // 65536 contiguous floats
  const float* xp = x + ((size_t)b * C_ + (size_t)g * CPG) * S_;
  float* hp = h + ((size_t)b * C_ + (size_t)g * CPG) * S_;
  int tid = threadIdx.x;
  float sum = 0.f, sumsq = 0.f;
  for (int i = tid; i < GS; i += 256) {
    float v = xp[i];
    sum += v; sumsq += v * v;
  }
  __shared__ float s1[256], s2[256];
  s1[tid] = sum; s2[tid] = sumsq;
  __syncthreads();
  for (int off = 128; off > 0; off >>= 1) {
    if (tid < off) { s1[tid] += s1[tid + off]; s2[tid] += s2[tid + off]; }
    __syncthreads();
  }
  float mean = s1[0] / (float)GS;
  float var = s2[0] / (float)GS - mean * mean;
  float inv = rsqrtf(var + EPS_GN);
  for (int i = tid; i < GS; i += 256) {
    int c = g * CPG + (i >> 10);       // i / S_
    hp[i] = (xp[i] - mean) * inv * scale[c] + bias[c];
  }
}

// ---------------- QKV GEMM (NN): per b, Out[m,n] = sum_k W[m,k]*H[b,k,n] + bias[m]
// M=1536, N=1024, K=512
__global__ __launch_bounds__(256) void gemm_qkv(
    const float* __restrict__ W, const float* __restrict__ Hin,
    const float* __restrict__ bias, float* __restrict__ Out) {
  const int M = 3 * C_, N = S_, K = C_;
  int b = blockIdx.z;
  int bm = blockIdx.y * 64, bn = blockIdx.x * 64;
  const float* Bg = Hin + (size_t)b * K * N;
  float* Og = Out + (size_t)b * M * N;
  __shared__ float As[16][64];
  __shared__ float Bs[16][64];
  int tid = threadIdx.x, tx = tid & 15, ty = tid >> 4;
  float acc[4][4] = {};
  for (int k0 = 0; k0 < K; k0 += 16) {
    #pragma unroll
    for (int r = 0; r < 4; ++r) {
      int lin = tid + r * 256;
      int m = lin >> 4, kk = lin & 15;
      As[kk][m] = W[(size_t)(bm + m) * K + k0 + kk];
    }
    #pragma unroll
    for (int r = 0; r < 4; ++r) {
      int lin = tid + r * 256;
      int kk = lin >> 6, n = lin & 63;
      Bs[kk][n] = Bg[(size_t)(k0 + kk) * N + bn + n];
    }
    __syncthreads();
    #pragma unroll
    for (int kk = 0; kk < 16; ++kk) {
      float a[4], bb[4];
      #pragma unroll
      for (int i = 0; i < 4; ++i) a[i] = As[kk][ty * 4 + i];
      #pragma unroll
      for (int j = 0; j < 4; ++j) bb[j] = Bs[kk][tx * 4 + j];
      #pragma unroll
      for (int i = 0; i < 4; ++i)
        #pragma unroll
        for (int j = 0; j < 4; ++j) acc[i][j] += a[i] * bb[j];
    }
    __syncthreads();
  }
  #pragma unroll
  for (int i = 0; i < 4; ++i) {
    int m = bm + ty * 4 + i;
    float bv = bias[m];
    #pragma unroll
    for (int j = 0; j < 4; ++j) {
      int n = bn + tx * 4 + j;
      Og[(size_t)m * N + n] = acc[i][j] + bv;
    }
  }
}

// ---------------- Attention: qkv[B,3C,S] -> hflat[B,S,C] ----------------
// Block: 256 thr = 4 waves, each wave 2 s-rows; 8 rows/block; 128 blocks per (b,n)
__global__ __launch_bounds__(256) void attn_kernel(
    const float* __restrict__ qkv, float* __restrict__ hflat) {
  int bid = blockIdx.x;                   // 64 * 128 = 8192
  const int blocksPerBn = S_ / 8;         // 128
  int bn = bid / blocksPerBn;
  int s_base = (bid % blocksPerBn) * 8;
  int b = bn >> 3, n = bn & 7;
  int tid = threadIdx.x, wave = tid >> 6, lane = tid & 63;

  const size_t bstride = (size_t)3 * C_ * S_;
  const float* Q = qkv + (size_t)b * bstride + (size_t)(n * HD) * S_;
  const float* Kp = Q + (size_t)C_ * S_;
  const float* Vp = Q + (size_t)2 * C_ * S_;

  __shared__ float q_lds[8][HD];
  __shared__ float kv_lds[HD][HD + 1];
  __shared__ float p_lds[8][S_];

  for (int idx = tid; idx < 8 * HD; idx += 256) {
    int r = idx >> 6, d = idx & 63;
    q_lds[r][d] = Q[(size_t)d * S_ + s_base + r];
  }

  float sc[2][16];
  for (int tt = 0; tt < 16; ++tt) {
    __syncthreads();   // protects prior-tile use (and q_lds on first iter)
    for (int idx = tid; idx < HD * 64; idx += 256) {
      int d = idx >> 6, tl = idx & 63;
      kv_lds[d][tl] = Kp[(size_t)d * S_ + (tt << 6) + tl];
    }
    __syncthreads();
    #pragma unroll
    for (int r = 0; r < 2; ++r) {
      int row = wave * 2 + r;
      float acc = 0.f;
      #pragma unroll
      for (int d = 0; d < HD; ++d) acc += q_lds[row][d] * kv_lds[d][lane];
      sc[r][tt] = acc * 0.125f;           // hd^-0.5
    }
  }

  #pragma unroll
  for (int r = 0; r < 2; ++r) {
    float m = -1e30f;
    #pragma unroll
    for (int tt = 0; tt < 16; ++tt) m = fmaxf(m, sc[r][tt]);
    for (int off = 32; off >= 1; off >>= 1) m = fmaxf(m, __shfl_xor(m, off, 64));
    float l = 0.f;
    #pragma unroll
    for (int tt = 0; tt < 16; ++tt) { float e = __expf(sc[r][tt] - m); sc[r][tt] = e; l += e; }
    for (int off = 32; off >= 1; off >>= 1) l += __shfl_xor(l, off, 64);
    float inv = 1.f / l;
    int row = wave * 2 + r;
    #pragma unroll
    for (int tt = 0; tt < 16; ++tt) p_lds[row][(tt << 6) + lane] = sc[r][tt] * inv;
  }

  float hacc[2] = {0.f, 0.f};
  for (int tt = 0; tt < 16; ++tt) {
    __syncthreads();   // protects K-tile use / p_lds writes on first iter
    for (int idx = tid; idx < HD * 64; idx += 256) {
      int d = idx >> 6, tl = idx & 63;
      kv_lds[d][tl] = Vp[(size_t)d * S_ + (tt << 6) + tl];
    }
    __syncthreads();
    #pragma unroll
    for (int r = 0; r < 2; ++r) {
      int row = wave * 2 + r;
      float a = 0.f;
      #pragma unroll
      for (int tl = 0; tl < 64; ++tl)
        a += p_lds[row][(tt << 6) + tl] * kv_lds[lane][tl];
      hacc[r] += a;
    }
  }
  #pragma unroll
  for (int r = 0; r < 2; ++r) {
    int s = s_base + wave * 2 + r;
    hflat[((size_t)b * S_ + s) * C_ + n * HD + lane] = hacc[r];
  }
}

// ---------------- INL step (NT): Out[m,o] = A[m,o] + dt*tanh(sum_c A[m,c]W[o,c] + b[o])
// M = B*S = 8192, N = K = 512
__global__ __launch_bounds__(256) void gemm_inl(
    const float* __restrict__ A, const float* __restrict__ W,
    const float* __restrict__ bias, float* __restrict__ Out) {
  const int N = C_, K = C_;
  int bm = blockIdx.y * 64, bn = blockIdx.x * 64;
  __shared__ float As[16][64];
  __shared__ float Bs[16][64];
  int tid = threadIdx.x, tx = tid & 15, ty = tid >> 4;
  float acc[4][4] = {};
  for (int k0 = 0; k0 < K; k0 += 16) {
    #pragma unroll
    for (int r = 0; r < 4; ++r) {
      int lin = tid + r * 256;
      int m = lin >> 4, kk = lin & 15;
      As[kk][m] = A[(size_t)(bm + m) * K + k0 + kk];
    }
    #pragma unroll
    for (int r = 0; r < 4; ++r) {
      int lin = tid + r * 256;
      int nn = lin >> 4, kk = lin & 15;
      Bs[kk][nn] = W[(size_t)(bn + nn) * K + k0 + kk];
    }
    __syncthreads();
    #pragma unroll
    for (int kk = 0; kk < 16; ++kk) {
      float a[4], bb[4];
      #pragma unroll
      for (int i = 0; i < 4; ++i) a[i] = As[kk][ty * 4 + i];
      #pragma unroll
      for (int j = 0; j < 4; ++j) bb[j] = Bs[kk][tx * 4 + j];
      #pragma unroll
      for (int i = 0; i < 4; ++i)
        #pragma unroll
        for (int j = 0; j < 4; ++j) acc[i][j] += a[i] * bb[j];
    }
    __syncthreads();
  }
  #pragma unroll
  for (int i = 0; i < 4; ++i) {
    int m = bm + ty * 4 + i;
    #pragma unroll
    for (int j = 0; j < 4; ++j) {
      int n = bn + tx * 4 + j;
      float t = tanhf(acc[i][j] + bias[n]);
      Out[(size_t)m * N + n] = A[(size_t)m * K + n] + DT_STEP * t;
    }
  }
}

// ---------------- Proj (NT) + residual: out[b,o,s] = x[b,o,s] + pb[o] + sum_c Pw[o,c]*Hf[b,s,c]
// per b: M=512 (o), N=1024 (s), K=512 (c)
__global__ __launch_bounds__(256) void gemm_proj(
    const float* __restrict__ Pw, const float* __restrict__ Hf,
    const float* __restrict__ pb, const float* __restrict__ x,
    float* __restrict__ Out) {
  const int N = S_, K = C_;
  int b = blockIdx.z;
  int bm = blockIdx.y * 64, bn = blockIdx.x * 64;
  const float* Bg = Hf + (size_t)b * S_ * C_;
  __shared__ float As[16][64];
  __shared__ float Bs[16][64];
  int tid = threadIdx.x, tx = tid & 15, ty = tid >> 4;
  float acc[4][4] = {};
  for (int k0 = 0; k0 < K; k0 += 16) {
    #pragma unroll
    for (int r = 0; r < 4; ++r) {
      int lin = tid + r * 256;
      int m = lin >> 4, kk = lin & 15;
      As[kk][m] = Pw[(size_t)(bm + m) * K + k0 + kk];
    }
    #pragma unroll
    for (int r = 0; r < 4; ++r) {
      int lin = tid + r * 256;
      int nn = lin >> 4, kk = lin & 15;
      Bs[kk][nn] = Bg[(size_t)(bn + nn) * K + k0 + kk];
    }
    __syncthreads();
    #pragma unroll
    for (int kk = 0; kk < 16; ++kk) {
      float a[4], bb[4];
      #pragma unroll
      for (int i = 0; i < 4; ++i) a[i] = As[kk][ty * 4 + i];
      #pragma unroll
      for (int j = 0; j < 4; ++j) bb[j] = Bs[kk][tx * 4 + j];
      #pragma unroll
      for (int i = 0; i < 4; ++i)
        #pragma unroll
        for (int j = 0; j < 4; ++j) acc[i][j] += a[i] * bb[j];
    }
    __syncthreads();
  }
  #pragma unroll
  for (int i = 0; i < 4; ++i) {
    int m = bm + ty * 4 + i;
    float bv = pb[m];
    #pragma unroll
    for (int j = 0; j < 4; ++j) {
      int n = bn + tx * 4 + j;
      size_t oidx = ((size_t)b * C_ + m) * S_ + n;
      Out[oidx] = x[oidx] + bv + acc[i][j];
    }
  }
}

extern "C" void kernel_launch(void* const* d_in, const int* in_sizes, int n_in,
                              void* d_out, int out_size, void* d_ws, size_t ws_size,
                              hipStream_t stream) {
  const float* x        = (const float*)d_in[0];
  const float* gn_scale = (const float*)d_in[1];
  const float* gn_bias  = (const float*)d_in[2];
  const float* qkv_w    = (const float*)d_in[3];
  const float* qkv_b    = (const float*)d_in[4];
  const float* proj_w   = (const float*)d_in[5];
  const float* proj_b   = (const float*)d_in[6];
  const float* inl_w    = (const float*)d_in[7];
  const float* inl_b    = (const float*)d_in[8];
  float* out = (float*)d_out;
  float* ws = (float*)d_ws;

  // ws layout (floats):
  //   [0, 4M)        h [B,C,S]; reused after QKV as wsA [B,S,C]
  //   [4M, 16M)      qkv [B,3C,S]
  //   [16M, 20M)     wsB [B,S,C]
  float* h    = ws;
  float* qkv  = ws + 4194304;
  float* wsA  = ws;          // aliases h (dead after QKV GEMM)
  float* wsB  = ws + 16777216;

  groupnorm_kernel<<<64, 256, 0, stream>>>(x, gn_scale, gn_bias, h);
  gemm_qkv<<<dim3(16, 24, 8), 256, 0, stream>>>(qkv_w, h, qkv_b, qkv);
  attn_kernel<<<8192, 256, 0, stream>>>(qkv, wsA);
  gemm_inl<<<dim3(8, 128), 256, 0, stream>>>(wsA, inl_w, inl_b, wsB);
  gemm_inl<<<dim3(8, 128), 256, 0, stream>>>(wsB, inl_w, inl_b, wsA);
  gemm_inl<<<dim3(8, 128), 256, 0, stream>>>(wsA, inl_w, inl_b, wsB);
  gemm_proj<<<dim3(16, 8, 8), 256, 0, stream>>>(proj_w, wsB, proj_b, x, out);
}

// Round 2
// 865.657 us; speedup vs baseline: 3.0772x; 3.0772x over previous
//
#include <hip/hip_runtime.h>
#include <math.h>

#define B_ 8
#define C_ 512
#define S_ 1024
#define HD 64
#define NHEADS 8
#define NGROUPS 8
#define DT_STEP 0.1f
#define EPS_GN 1e-5f

typedef __attribute__((ext_vector_type(8))) short bf16x8;
typedef __attribute__((ext_vector_type(4))) float f32x4;
typedef __attribute__((ext_vector_type(8))) unsigned short ushort8;

static __device__ __forceinline__ unsigned short f2bf(float f) {
  unsigned int u = __builtin_bit_cast(unsigned int, f);
  u += 0x7fff + ((u >> 16) & 1);           // round-to-nearest-even
  return (unsigned short)(u >> 16);
}

// ---------------- GroupNorm: x[B,C,S] -> h[B,C,S] ----------------
__global__ __launch_bounds__(256) void groupnorm_kernel(
    const float* __restrict__ x, const float* __restrict__ scale,
    const float* __restrict__ bias, float* __restrict__ h) {
  int bg = blockIdx.x;                 // B*NGROUPS = 64
  int b = bg / NGROUPS, g = bg % NGROUPS;
  const int CPG = C_ / NGROUPS;        // 64
  const int GS = CPG * S_;             // 65536 contiguous floats
  const float* xp = x + ((size_t)b * C_ + (size_t)g * CPG) * S_;
  float* hp = h + ((size_t)b * C_ + (size_t)g * CPG) * S_;
  int tid = threadIdx.x;
  float sum = 0.f, sumsq = 0.f;
  for (int i = tid; i < GS; i += 256) {
    float v = xp[i];
    sum += v; sumsq += v * v;
  }
  __shared__ float s1[256], s2[256];
  s1[tid] = sum; s2[tid] = sumsq;
  __syncthreads();
  for (int off = 128; off > 0; off >>= 1) {
    if (tid < off) { s1[tid] += s1[tid + off]; s2[tid] += s2[tid + off]; }
    __syncthreads();
  }
  float mean = s1[0] / (float)GS;
  float var = s2[0] / (float)GS - mean * mean;
  float inv = rsqrtf(var + EPS_GN);
  for (int i = tid; i < GS; i += 256) {
    int c = g * CPG + (i >> 10);       // i / S_
    hp[i] = (xp[i] - mean) * inv * scale[c] + bias[c];
  }
}

// ---------------- QKV GEMM (NN), bf16 output: per b, Out[m,n] = sum_k W[m,k]*H[b,k,n] + bias[m]
// M=1536, N=1024, K=512
__global__ __launch_bounds__(256) void gemm_qkv(
    const float* __restrict__ W, const float* __restrict__ Hin,
    const float* __restrict__ bias, unsigned short* __restrict__ Out) {
  const int M = 3 * C_, N = S_, K = C_;
  int b = blockIdx.z;
  int bm = blockIdx.y * 64, bn = blockIdx.x * 64;
  const float* Bg = Hin + (size_t)b * K * N;
  unsigned short* Og = Out + (size_t)b * M * N;
  __shared__ float As[16][64];
  __shared__ float Bs[16][64];
  int tid = threadIdx.x, tx = tid & 15, ty = tid >> 4;
  float acc[4][4] = {};
  for (int k0 = 0; k0 < K; k0 += 16) {
    #pragma unroll
    for (int r = 0; r < 4; ++r) {
      int lin = tid + r * 256;
      int m = lin >> 4, kk = lin & 15;
      As[kk][m] = W[(size_t)(bm + m) * K + k0 + kk];
    }
    #pragma unroll
    for (int r = 0; r < 4; ++r) {
      int lin = tid + r * 256;
      int kk = lin >> 6, n = lin & 63;
      Bs[kk][n] = Bg[(size_t)(k0 + kk) * N + bn + n];
    }
    __syncthreads();
    #pragma unroll
    for (int kk = 0; kk < 16; ++kk) {
      float a[4], bb[4];
      #pragma unroll
      for (int i = 0; i < 4; ++i) a[i] = As[kk][ty * 4 + i];
      #pragma unroll
      for (int j = 0; j < 4; ++j) bb[j] = Bs[kk][tx * 4 + j];
      #pragma unroll
      for (int i = 0; i < 4; ++i)
        #pragma unroll
        for (int j = 0; j < 4; ++j) acc[i][j] += a[i] * bb[j];
    }
    __syncthreads();
  }
  #pragma unroll
  for (int i = 0; i < 4; ++i) {
    int m = bm + ty * 4 + i;
    float bv = bias[m];
    #pragma unroll
    for (int j = 0; j < 4; ++j) {
      int n = bn + tx * 4 + j;
      Og[(size_t)m * N + n] = f2bf(acc[i][j] + bv);
    }
  }
}

// ---------------- Transpose Q,K to [b][n][row][d] bf16 ----------------
__global__ __launch_bounds__(256) void transpose_qk(
    const unsigned short* __restrict__ qkv_bf,
    unsigned short* __restrict__ Qt, unsigned short* __restrict__ Kt) {
  __shared__ unsigned short lds[64][72];
  int bid = blockIdx.x;                // b*256 + hc*16 + st
  int st = bid & 15, hc = (bid >> 4) & 15, b = bid >> 8;
  int tensor = hc >> 3, n = hc & 7;
  int s0 = st * 64;
  const unsigned short* src = qkv_bf + ((size_t)b * 1536 + tensor * 512 + n * 64) * 1024;
  unsigned short* dst = (tensor ? Kt : Qt) + (((size_t)(b * 8 + n)) * 1024 + s0) * 64;
  int tid = threadIdx.x;
  #pragma unroll
  for (int it = 0; it < 2; ++it) {
    int idx = tid + it * 256;
    int d = idx >> 3, c8 = (idx & 7) * 8;
    *(ushort8*)&lds[d][c8] = *(const ushort8*)(src + (size_t)d * 1024 + s0 + c8);
  }
  __syncthreads();
  #pragma unroll
  for (int it = 0; it < 2; ++it) {
    int idx = tid + it * 256;
    int s = idx >> 3, d8 = (idx & 7) * 8;
    ushort8 v;
    #pragma unroll
    for (int j = 0; j < 8; ++j) v[j] = lds[d8 + j][s];
    *(ushort8*)(dst + (size_t)s * 64 + d8) = v;
  }
}

// ---------------- Flash attention, bf16 MFMA ----------------
// grid: 1024 blocks = (b*8+n)*16 + sblk ; 256 thr = 4 waves x 16 q-rows
__global__ __launch_bounds__(256) void attn_mfma(
    const unsigned short* __restrict__ Qt,   // [B][NH][S][HD]
    const unsigned short* __restrict__ Kt,   // [B][NH][S][HD]
    const unsigned short* __restrict__ qkv_bf, // V natural: [B][3C][S]
    float* __restrict__ hflat) {             // [B][S][C]
  int tid = threadIdx.x, wave = tid >> 6, lane = tid & 63;
  int quad = lane >> 4, l15 = lane & 15;
  int bid = blockIdx.x;
  int sblk = bid & 15, bn = bid >> 4, b = bn >> 3, n = bn & 7;
  int s0w = sblk * 64 + wave * 16;

  __shared__ unsigned short k_lds[64][72];        // [t_local][d]
  __shared__ unsigned short v_lds[64][72];        // [d][t_local]
  __shared__ unsigned short p_lds[4][16][72];     // per-wave [s_local][t_local]

  const unsigned short* Qb = Qt + (((size_t)(b * 8 + n)) * 1024 + s0w + l15) * 64;
  const unsigned short* Kb = Kt + ((size_t)(b * 8 + n)) * 1024 * 64;
  const unsigned short* Vb = qkv_bf + ((size_t)b * 1536 + 1024 + n * 64) * 1024;

  bf16x8 qa0 = *(const bf16x8*)(Qb + quad * 8);
  bf16x8 qa1 = *(const bf16x8*)(Qb + 32 + quad * 8);

  f32x4 o_acc[4];
  float m_run[4], l_run[4];
  #pragma unroll
  for (int r = 0; r < 4; ++r) { m_run[r] = -INFINITY; l_run[r] = 0.f; }
  #pragma unroll
  for (int dc = 0; dc < 4; ++dc) o_acc[dc] = (f32x4){0.f, 0.f, 0.f, 0.f};

  for (int t0 = 0; t0 < S_; t0 += 64) {
    __syncthreads();   // previous tile fully consumed
    #pragma unroll
    for (int it = 0; it < 2; ++it) {
      int idx = tid + it * 256;
      int row = idx >> 3, c8 = (idx & 7) * 8;
      *(ushort8*)&k_lds[row][c8] = *(const ushort8*)(Kb + (size_t)(t0 + row) * 64 + c8);
      *(ushort8*)&v_lds[row][c8] = *(const ushort8*)(Vb + (size_t)row * 1024 + t0 + c8);
    }
    __syncthreads();

    // QK^T: sc[tc] covers s=(s0w+quad*4+r), t=(t0+tc*16+l15)
    f32x4 sc[4];
    #pragma unroll
    for (int tc = 0; tc < 4; ++tc) {
      bf16x8 kb0 = *(const bf16x8*)&k_lds[tc * 16 + l15][quad * 8];
      bf16x8 kb1 = *(const bf16x8*)&k_lds[tc * 16 + l15][32 + quad * 8];
      f32x4 c = {0.f, 0.f, 0.f, 0.f};
      c = __builtin_amdgcn_mfma_f32_16x16x32_bf16(qa0, kb0, c, 0, 0, 0);
      c = __builtin_amdgcn_mfma_f32_16x16x32_bf16(qa1, kb1, c, 0, 0, 0);
      sc[tc] = c * 0.125f;               // hd^-0.5
    }

    // online softmax per row (rows = quad*4+r, replicated over 16 l15 lanes)
    float alpha[4];
    #pragma unroll
    for (int r = 0; r < 4; ++r) {
      float mx = fmaxf(fmaxf(sc[0][r], sc[1][r]), fmaxf(sc[2][r], sc[3][r]));
      mx = fmaxf(mx, __shfl_xor(mx, 1, 64));
      mx = fmaxf(mx, __shfl_xor(mx, 2, 64));
      mx = fmaxf(mx, __shfl_xor(mx, 4, 64));
      mx = fmaxf(mx, __shfl_xor(mx, 8, 64));
      float mnew = fmaxf(m_run[r], mx);
      float a = __expf(m_run[r] - mnew);
      float sum = 0.f;
      #pragma unroll
      for (int tc = 0; tc < 4; ++tc) {
        float e = __expf(sc[tc][r] - mnew);
        sc[tc][r] = e;
        sum += e;
      }
      sum += __shfl_xor(sum, 1, 64);
      sum += __shfl_xor(sum, 2, 64);
      sum += __shfl_xor(sum, 4, 64);
      sum += __shfl_xor(sum, 8, 64);
      l_run[r] = l_run[r] * a + sum;
      m_run[r] = mnew;
      alpha[r] = a;
    }
    #pragma unroll
    for (int dc = 0; dc < 4; ++dc)
      #pragma unroll
      for (int r = 0; r < 4; ++r) o_acc[dc][r] *= alpha[r];

    // P: C-layout -> LDS -> A-layout (wave-local region, no barrier)
    #pragma unroll
    for (int tc = 0; tc < 4; ++tc)
      #pragma unroll
      for (int r = 0; r < 4; ++r)
        p_lds[wave][quad * 4 + r][tc * 16 + l15] = f2bf(sc[tc][r]);

    bf16x8 pa0 = *(const bf16x8*)&p_lds[wave][l15][quad * 8];
    bf16x8 pa1 = *(const bf16x8*)&p_lds[wave][l15][32 + quad * 8];
    #pragma unroll
    for (int dc = 0; dc < 4; ++dc) {
      bf16x8 vb0 = *(const bf16x8*)&v_lds[dc * 16 + l15][quad * 8];
      bf16x8 vb1 = *(const bf16x8*)&v_lds[dc * 16 + l15][32 + quad * 8];
      o_acc[dc] = __builtin_amdgcn_mfma_f32_16x16x32_bf16(pa0, vb0, o_acc[dc], 0, 0, 0);
      o_acc[dc] = __builtin_amdgcn_mfma_f32_16x16x32_bf16(pa1, vb1, o_acc[dc], 0, 0, 0);
    }
  }

  #pragma unroll
  for (int dc = 0; dc < 4; ++dc) {
    #pragma unroll
    for (int r = 0; r < 4; ++r) {
      int s = s0w + quad * 4 + r;
      hflat[((size_t)b * S_ + s) * C_ + n * HD + dc * 16 + l15] = o_acc[dc][r] / l_run[r];
    }
  }
}

// ---------------- INL step (NT): Out[m,o] = A[m,o] + dt*tanh(sum_c A[m,c]W[o,c] + b[o])
// M = B*S = 8192, N = K = 512
__global__ __launch_bounds__(256) void gemm_inl(
    const float* __restrict__ A, const float* __restrict__ W,
    const float* __restrict__ bias, float* __restrict__ Out) {
  const int N = C_, K = C_;
  int bm = blockIdx.y * 64, bn = blockIdx.x * 64;
  __shared__ float As[16][64];
  __shared__ float Bs[16][64];
  int tid = threadIdx.x, tx = tid & 15, ty = tid >> 4;
  float acc[4][4] = {};
  for (int k0 = 0; k0 < K; k0 += 16) {
    #pragma unroll
    for (int r = 0; r < 4; ++r) {
      int lin = tid + r * 256;
      int m = lin >> 4, kk = lin & 15;
      As[kk][m] = A[(size_t)(bm + m) * K + k0 + kk];
    }
    #pragma unroll
    for (int r = 0; r < 4; ++r) {
      int lin = tid + r * 256;
      int nn = lin >> 4, kk = lin & 15;
      Bs[kk][nn] = W[(size_t)(bn + nn) * K + k0 + kk];
    }
    __syncthreads();
    #pragma unroll
    for (int kk = 0; kk < 16; ++kk) {
      float a[4], bb[4];
      #pragma unroll
      for (int i = 0; i < 4; ++i) a[i] = As[kk][ty * 4 + i];
      #pragma unroll
      for (int j = 0; j < 4; ++j) bb[j] = Bs[kk][tx * 4 + j];
      #pragma unroll
      for (int i = 0; i < 4; ++i)
        #pragma unroll
        for (int j = 0; j < 4; ++j) acc[i][j] += a[i] * bb[j];
    }
    __syncthreads();
  }
  #pragma unroll
  for (int i = 0; i < 4; ++i) {
    int m = bm + ty * 4 + i;
    #pragma unroll
    for (int j = 0; j < 4; ++j) {
      int n = bn + tx * 4 + j;
      float t = tanhf(acc[i][j] + bias[n]);
      Out[(size_t)m * N + n] = A[(size_t)m * K + n] + DT_STEP * t;
    }
  }
}

// ---------------- Proj (NT) + residual: out[b,o,s] = x[b,o,s] + pb[o] + sum_c Pw[o,c]*Hf[b,s,c]
__global__ __launch_bounds__(256) void gemm_proj(
    const float* __restrict__ Pw, const float* __restrict__ Hf,
    const float* __restrict__ pb, const float* __restrict__ x,
    float* __restrict__ Out) {
  const int N = S_, K = C_;
  int b = blockIdx.z;
  int bm = blockIdx.y * 64, bn = blockIdx.x * 64;
  const float* Bg = Hf + (size_t)b * S_ * C_;
  __shared__ float As[16][64];
  __shared__ float Bs[16][64];
  int tid = threadIdx.x, tx = tid & 15, ty = tid >> 4;
  float acc[4][4] = {};
  for (int k0 = 0; k0 < K; k0 += 16) {
    #pragma unroll
    for (int r = 0; r < 4; ++r) {
      int lin = tid + r * 256;
      int m = lin >> 4, kk = lin & 15;
      As[kk][m] = Pw[(size_t)(bm + m) * K + k0 + kk];
    }
    #pragma unroll
    for (int r = 0; r < 4; ++r) {
      int lin = tid + r * 256;
      int nn = lin >> 4, kk = lin & 15;
      Bs[kk][nn] = Bg[(size_t)(bn + nn) * K + k0 + kk];
    }
    __syncthreads();
    #pragma unroll
    for (int kk = 0; kk < 16; ++kk) {
      float a[4], bb[4];
      #pragma unroll
      for (int i = 0; i < 4; ++i) a[i] = As[kk][ty * 4 + i];
      #pragma unroll
      for (int j = 0; j < 4; ++j) bb[j] = Bs[kk][tx * 4 + j];
      #pragma unroll
      for (int i = 0; i < 4; ++i)
        #pragma unroll
        for (int j = 0; j < 4; ++j) acc[i][j] += a[i] * bb[j];
    }
    __syncthreads();
  }
  #pragma unroll
  for (int i = 0; i < 4; ++i) {
    int m = bm + ty * 4 + i;
    float bv = pb[m];
    #pragma unroll
    for (int j = 0; j < 4; ++j) {
      int n = bn + tx * 4 + j;
      size_t oidx = ((size_t)b * C_ + m) * S_ + n;
      Out[oidx] = x[oidx] + bv + acc[i][j];
    }
  }
}

extern "C" void kernel_launch(void* const* d_in, const int* in_sizes, int n_in,
                              void* d_out, int out_size, void* d_ws, size_t ws_size,
                              hipStream_t stream) {
  const float* x        = (const float*)d_in[0];
  const float* gn_scale = (const float*)d_in[1];
  const float* gn_bias  = (const float*)d_in[2];
  const float* qkv_w    = (const float*)d_in[3];
  const float* qkv_b    = (const float*)d_in[4];
  const float* proj_w   = (const float*)d_in[5];
  const float* proj_b   = (const float*)d_in[6];
  const float* inl_w    = (const float*)d_in[7];
  const float* inl_b    = (const float*)d_in[8];
  float* out = (float*)d_out;
  float* ws = (float*)d_ws;

  // ws layout (float offsets):
  //   [0, 4M)          h [B,C,S] fp32; later aliased as wsA [B,S,C]
  //   [4M, 10.5M)      qkv_bf [B,3C,S] bf16 (12.6M ushort)
  //   [12M, 14M)       Qt [B,NH,S,HD] bf16
  //   [14M, 16M)       Kt [B,NH,S,HD] bf16
  //   [16M, 20M)       wsB [B,S,C] fp32
  float* h = ws;
  unsigned short* qkv_bf = (unsigned short*)(ws + 4194304);
  unsigned short* Qt = (unsigned short*)(ws + 12582912);
  unsigned short* Kt = (unsigned short*)(ws + 14680064);
  float* wsA = ws;
  float* wsB = ws + 16777216;

  groupnorm_kernel<<<64, 256, 0, stream>>>(x, gn_scale, gn_bias, h);
  gemm_qkv<<<dim3(16, 24, 8), 256, 0, stream>>>(qkv_w, h, qkv_b, qkv_bf);
  transpose_qk<<<2048, 256, 0, stream>>>(qkv_bf, Qt, Kt);
  attn_mfma<<<1024, 256, 0, stream>>>(Qt, Kt, qkv_bf, wsA);
  gemm_inl<<<dim3(8, 128), 256, 0, stream>>>(wsA, inl_w, inl_b, wsB);
  gemm_inl<<<dim3(8, 128), 256, 0, stream>>>(wsB, inl_w, inl_b, wsA);
  gemm_inl<<<dim3(8, 128), 256, 0, stream>>>(wsA, inl_w, inl_b, wsB);
  gemm_proj<<<dim3(16, 8, 8), 256, 0, stream>>>(proj_w, wsB, proj_b, x, out);
}

// Round 3
// 276.784 us; speedup vs baseline: 9.6240x; 3.1276x over previous
//
#include <hip/hip_runtime.h>
#include <math.h>

#define B_ 8
#define C_ 512
#define S_ 1024
#define HD 64
#define NHEADS 8
#define NGROUPS 8
#define DT_STEP 0.1f
#define EPS_GN 1e-5f

typedef __attribute__((ext_vector_type(8))) short bf16x8;
typedef __attribute__((ext_vector_type(4))) float f32x4;
typedef __attribute__((ext_vector_type(8))) unsigned short ushort8;
typedef __attribute__((ext_vector_type(4))) unsigned short ushort4_t;

static __device__ __forceinline__ unsigned short f2bf(float f) {
  unsigned int u = __builtin_bit_cast(unsigned int, f);
  u += 0x7fff + ((u >> 16) & 1);           // round-to-nearest-even
  return (unsigned short)(u >> 16);
}

static __device__ __forceinline__ float fast_tanh(float x) {
  float xc = fminf(fmaxf(x, -15.f), 15.f);
  float e = __expf(2.f * xc);
  return (e - 1.f) / (e + 1.f);
}

static __device__ __forceinline__ void load16_lds(const void* g, void* l) {
  __builtin_amdgcn_global_load_lds((const __attribute__((address_space(1))) void*)g,
                                   (__attribute__((address_space(3))) void*)l, 16, 0, 0);
}

// ---------------- cast fp32 weights -> bf16 ----------------
__global__ __launch_bounds__(256) void cast3_kernel(
    const float* __restrict__ a, const float* __restrict__ b, const float* __restrict__ c,
    unsigned short* __restrict__ A, unsigned short* __restrict__ B, unsigned short* __restrict__ C) {
  int bid = blockIdx.x;
  const float* src; unsigned short* dst; int off;
  if (bid < 384) { src = a; dst = A; off = bid * 2048; }
  else if (bid < 512) { src = b; dst = B; off = (bid - 384) * 2048; }
  else { src = c; dst = C; off = (bid - 512) * 2048; }
  int i = off + threadIdx.x * 8;
  f32x4 v0 = *(const f32x4*)(src + i);
  f32x4 v1 = *(const f32x4*)(src + i + 4);
  ushort8 o;
  o[0] = f2bf(v0[0]); o[1] = f2bf(v0[1]); o[2] = f2bf(v0[2]); o[3] = f2bf(v0[3]);
  o[4] = f2bf(v1[0]); o[5] = f2bf(v1[1]); o[6] = f2bf(v1[2]); o[7] = f2bf(v1[3]);
  *(ushort8*)(dst + i) = o;
}

// ---------------- GroupNorm + transpose: x[B,C,S] -> h_t[B,S,C] bf16 ----------------
__global__ __launch_bounds__(256) void groupnorm_t(
    const float* __restrict__ x, const float* __restrict__ scale,
    const float* __restrict__ bias, unsigned short* __restrict__ h_t) {
  int bg = blockIdx.x;                 // B*NGROUPS = 64
  int b = bg / NGROUPS, g = bg % NGROUPS;
  const int CPG = 64;
  const int GS = CPG * S_;             // 65536
  const float* xp = x + ((size_t)b * C_ + (size_t)g * CPG) * S_;
  int tid = threadIdx.x;
  float sum = 0.f, sumsq = 0.f;
  for (int i = tid * 4; i < GS; i += 1024) {
    f32x4 v = *(const f32x4*)(xp + i);
    sum += v[0] + v[1] + v[2] + v[3];
    sumsq += v[0]*v[0] + v[1]*v[1] + v[2]*v[2] + v[3]*v[3];
  }
  __shared__ float s1[256], s2[256];
  s1[tid] = sum; s2[tid] = sumsq;
  __syncthreads();
  for (int off = 128; off > 0; off >>= 1) {
    if (tid < off) { s1[tid] += s1[tid + off]; s2[tid] += s2[tid + off]; }
    __syncthreads();
  }
  float mean = s1[0] / (float)GS;
  float var = s2[0] / (float)GS - mean * mean;
  float inv = rsqrtf(var + EPS_GN);

  int sl = tid >> 2;                   // s within tile
  int cq = (tid & 3) * 16;             // c base within group
  float sA[16], sB[16];
  #pragma unroll
  for (int u = 0; u < 16; ++u) {
    float scv = scale[g * 64 + cq + u];
    sA[u] = inv * scv;
    sB[u] = bias[g * 64 + cq + u] - mean * inv * scv;
  }

  __shared__ float tile[64][65];
  for (int st = 0; st < 16; ++st) {
    __syncthreads();
    #pragma unroll
    for (int it = 0; it < 16; ++it) {
      int lin = it * 256 + tid;        // 4096 = 64c x 64s
      int c = lin >> 6, s = lin & 63;
      tile[c][s] = xp[(size_t)c * S_ + st * 64 + s];
    }
    __syncthreads();
    unsigned short vals[16];
    #pragma unroll
    for (int u = 0; u < 16; ++u)
      vals[u] = f2bf(tile[cq + u][sl] * sA[u] + sB[u]);
    unsigned short* dst = h_t + ((size_t)b * S_ + st * 64 + sl) * C_ + g * 64 + cq;
    ushort8 lo, hi;
    #pragma unroll
    for (int u = 0; u < 8; ++u) { lo[u] = vals[u]; hi[u] = vals[u + 8]; }
    *(ushort8*)dst = lo;
    *(ushort8*)(dst + 8) = hi;
  }
}

// ---------------- NT GEMM core: C[MB,NB] = A[MB,K=512] * B[NB,K=512]^T ----------------
// A,B bf16 k-contiguous. 256 threads. Wave grid WMG x WNG.
template<int MB, int NB, int WMG, int WNG>
__device__ __forceinline__ void gemm_nt_core(
    const unsigned short* __restrict__ Ab,   // + bm*K
    const unsigned short* __restrict__ Bb,   // + bn*K
    unsigned short* ldsA, unsigned short* ldsB,
    f32x4* acc) {                            // [TI*TJ]
  constexpr int TI = (MB / WMG) / 16;
  constexpr int TJ = (NB / WNG) / 16;
  constexpr int NQA = MB * 4 / 256;          // 16B chunks per thread for A tile
  constexpr int NQB = NB * 4 / 256;
  const int K = 512;
  const int tid = threadIdx.x;
  const int w = tid >> 6, lane = tid & 63, quad = lane >> 4, l15 = lane & 15;
  const int wm = (WNG == 1) ? w : ((WMG == 1) ? 0 : (w >> 1));
  const int wn = (WNG == 1) ? 0 : ((WMG == 1) ? w : (w & 1));

  for (int k0 = 0; k0 < K; k0 += 32) {
    __syncthreads();
    #pragma unroll
    for (int q = 0; q < NQA; ++q) {
      int c = q * 256 + tid;
      load16_lds(Ab + (size_t)(c >> 2) * K + k0 + (c & 3) * 8, ldsA + c * 8);
    }
    #pragma unroll
    for (int q = 0; q < NQB; ++q) {
      int c = q * 256 + tid;
      load16_lds(Bb + (size_t)(c >> 2) * K + k0 + (c & 3) * 8, ldsB + c * 8);
    }
    __syncthreads();
    bf16x8 af[TI], bf[TJ];
    #pragma unroll
    for (int i = 0; i < TI; ++i)
      af[i] = *(const bf16x8*)(ldsA + (wm * (MB / WMG) + i * 16 + l15) * 32 + quad * 8);
    #pragma unroll
    for (int j = 0; j < TJ; ++j)
      bf[j] = *(const bf16x8*)(ldsB + (wn * (NB / WNG) + j * 16 + l15) * 32 + quad * 8);
    #pragma unroll
    for (int i = 0; i < TI; ++i)
      #pragma unroll
      for (int j = 0; j < TJ; ++j)
        acc[i * TJ + j] = __builtin_amdgcn_mfma_f32_16x16x32_bf16(af[i], bf[j], acc[i * TJ + j], 0, 0, 0);
  }
}

// ---------------- QKV GEMM: W_bf[1536,512] x h_t[b][1024,512]^T ----------------
// Epilogue scatters Q,K -> [b,head,s,d] and V -> [b,c,s]
__global__ __launch_bounds__(256) void gemm_qkv_mfma(
    const unsigned short* __restrict__ Wbf, const unsigned short* __restrict__ h_t,
    const float* __restrict__ bias,
    unsigned short* __restrict__ Qt, unsigned short* __restrict__ Kt,
    unsigned short* __restrict__ Vt) {
  __shared__ __align__(16) unsigned short ldsA[128 * 32];
  __shared__ __align__(16) unsigned short ldsB[128 * 32];
  int b = blockIdx.z;
  int bm = blockIdx.y * 128, bn = blockIdx.x * 128;
  f32x4 acc[16];
  #pragma unroll
  for (int t = 0; t < 16; ++t) acc[t] = (f32x4){0.f, 0.f, 0.f, 0.f};
  gemm_nt_core<128, 128, 2, 2>(Wbf + (size_t)bm * 512,
                               h_t + ((size_t)b * S_ + bn) * 512, ldsA, ldsB, acc);
  int tid = threadIdx.x, w = tid >> 6, lane = tid & 63, quad = lane >> 4, l15 = lane & 15;
  int wm = w >> 1, wn = w & 1;
  int tensor = bm >> 9;                 // block entirely inside one of Q/K/V
  #pragma unroll
  for (int i = 0; i < 4; ++i) {
    #pragma unroll
    for (int j = 0; j < 4; ++j) {
      int m0 = bm + wm * 64 + i * 16 + quad * 4;
      int ng = bn + wn * 64 + j * 16 + l15;
      f32x4 v = acc[i * 4 + j];
      if (tensor < 2) {
        int head = (m0 >> 6) & 7, d0 = m0 & 63;
        ushort4_t pk;
        #pragma unroll
        for (int r = 0; r < 4; ++r) pk[r] = f2bf(v[r] + bias[m0 + r]);
        unsigned short* dst = (tensor ? Kt : Qt) +
            (((size_t)(b * 8 + head) * S_ + ng) * 64 + d0);
        *(ushort4_t*)dst = pk;
      } else {
        #pragma unroll
        for (int r = 0; r < 4; ++r)
          Vt[(size_t)b * (C_ * S_) + (size_t)(m0 - 1024 + r) * S_ + ng] = f2bf(v[r] + bias[m0 + r]);
      }
    }
  }
}

// ---------------- Flash attention, bf16 MFMA ----------------
__global__ __launch_bounds__(256) void attn_mfma(
    const unsigned short* __restrict__ Qt,   // [B][NH][S][HD]
    const unsigned short* __restrict__ Kt,   // [B][NH][S][HD]
    const unsigned short* __restrict__ Vt,   // [B][C][S]
    float* __restrict__ hflat,               // [B][S][C] fp32
    unsigned short* __restrict__ hflat_bf) { // [B][S][C] bf16
  int tid = threadIdx.x, wave = tid >> 6, lane = tid & 63;
  int quad = lane >> 4, l15 = lane & 15;
  int bid = blockIdx.x;
  int sblk = bid & 15, bn = bid >> 4, b = bn >> 3, n = bn & 7;
  int s0w = sblk * 64 + wave * 16;

  __shared__ unsigned short k_lds[64][72];
  __shared__ unsigned short v_lds[64][72];
  __shared__ unsigned short p_lds[4][16][72];

  const unsigned short* Qb = Qt + (((size_t)(b * 8 + n)) * S_ + s0w + l15) * 64;
  const unsigned short* Kb = Kt + ((size_t)(b * 8 + n)) * S_ * 64;
  const unsigned short* Vb = Vt + ((size_t)b * C_ + n * 64) * S_;

  bf16x8 qa0 = *(const bf16x8*)(Qb + quad * 8);
  bf16x8 qa1 = *(const bf16x8*)(Qb + 32 + quad * 8);

  f32x4 o_acc[4];
  float m_run[4], l_run[4];
  #pragma unroll
  for (int r = 0; r < 4; ++r) { m_run[r] = -INFINITY; l_run[r] = 0.f; }
  #pragma unroll
  for (int dc = 0; dc < 4; ++dc) o_acc[dc] = (f32x4){0.f, 0.f, 0.f, 0.f};

  for (int t0 = 0; t0 < S_; t0 += 64) {
    __syncthreads();
    #pragma unroll
    for (int it = 0; it < 2; ++it) {
      int idx = tid + it * 256;
      int row = idx >> 3, c8 = (idx & 7) * 8;
      *(ushort8*)&k_lds[row][c8] = *(const ushort8*)(Kb + (size_t)(t0 + row) * 64 + c8);
      *(ushort8*)&v_lds[row][c8] = *(const ushort8*)(Vb + (size_t)row * S_ + t0 + c8);
    }
    __syncthreads();

    f32x4 sc[4];
    #pragma unroll
    for (int tc = 0; tc < 4; ++tc) {
      bf16x8 kb0 = *(const bf16x8*)&k_lds[tc * 16 + l15][quad * 8];
      bf16x8 kb1 = *(const bf16x8*)&k_lds[tc * 16 + l15][32 + quad * 8];
      f32x4 c = {0.f, 0.f, 0.f, 0.f};
      c = __builtin_amdgcn_mfma_f32_16x16x32_bf16(qa0, kb0, c, 0, 0, 0);
      c = __builtin_amdgcn_mfma_f32_16x16x32_bf16(qa1, kb1, c, 0, 0, 0);
      sc[tc] = c * 0.125f;
    }

    float alpha[4];
    #pragma unroll
    for (int r = 0; r < 4; ++r) {
      float mx = fmaxf(fmaxf(sc[0][r], sc[1][r]), fmaxf(sc[2][r], sc[3][r]));
      mx = fmaxf(mx, __shfl_xor(mx, 1, 64));
      mx = fmaxf(mx, __shfl_xor(mx, 2, 64));
      mx = fmaxf(mx, __shfl_xor(mx, 4, 64));
      mx = fmaxf(mx, __shfl_xor(mx, 8, 64));
      float mnew = fmaxf(m_run[r], mx);
      float a = __expf(m_run[r] - mnew);
      float sum = 0.f;
      #pragma unroll
      for (int tc = 0; tc < 4; ++tc) {
        float e = __expf(sc[tc][r] - mnew);
        sc[tc][r] = e;
        sum += e;
      }
      sum += __shfl_xor(sum, 1, 64);
      sum += __shfl_xor(sum, 2, 64);
      sum += __shfl_xor(sum, 4, 64);
      sum += __shfl_xor(sum, 8, 64);
      l_run[r] = l_run[r] * a + sum;
      m_run[r] = mnew;
      alpha[r] = a;
    }
    #pragma unroll
    for (int dc = 0; dc < 4; ++dc)
      #pragma unroll
      for (int r = 0; r < 4; ++r) o_acc[dc][r] *= alpha[r];

    #pragma unroll
    for (int tc = 0; tc < 4; ++tc)
      #pragma unroll
      for (int r = 0; r < 4; ++r)
        p_lds[wave][quad * 4 + r][tc * 16 + l15] = f2bf(sc[tc][r]);

    bf16x8 pa0 = *(const bf16x8*)&p_lds[wave][l15][quad * 8];
    bf16x8 pa1 = *(const bf16x8*)&p_lds[wave][l15][32 + quad * 8];
    #pragma unroll
    for (int dc = 0; dc < 4; ++dc) {
      bf16x8 vb0 = *(const bf16x8*)&v_lds[dc * 16 + l15][quad * 8];
      bf16x8 vb1 = *(const bf16x8*)&v_lds[dc * 16 + l15][32 + quad * 8];
      o_acc[dc] = __builtin_amdgcn_mfma_f32_16x16x32_bf16(pa0, vb0, o_acc[dc], 0, 0, 0);
      o_acc[dc] = __builtin_amdgcn_mfma_f32_16x16x32_bf16(pa1, vb1, o_acc[dc], 0, 0, 0);
    }
  }

  #pragma unroll
  for (int dc = 0; dc < 4; ++dc) {
    #pragma unroll
    for (int r = 0; r < 4; ++r) {
      int s = s0w + quad * 4 + r;
      size_t idx = ((size_t)b * S_ + s) * C_ + n * 64 + dc * 16 + l15;
      float val = o_acc[dc][r] / l_run[r];
      hflat[idx] = val;
      hflat_bf[idx] = f2bf(val);
    }
  }
}

// ---------------- INL step: h' = h + dt*tanh(h W^T + b), bf16 MFMA, fp32 residual ----------------
// A = hbf[8192,512], B = Wbf[512,512]. MB=128,NB=64, waves 4x1.
__global__ __launch_bounds__(256) void gemm_inl_mfma(
    const unsigned short* __restrict__ hbf_in, const unsigned short* __restrict__ Wbf,
    const float* __restrict__ bias, const float* __restrict__ h32_in,
    float* __restrict__ h32_out, unsigned short* __restrict__ hbf_out) {
  __shared__ __align__(16) unsigned short ldsA[128 * 32];
  __shared__ __align__(16) unsigned short ldsB[64 * 32];
  int bm = blockIdx.y * 128, bn = blockIdx.x * 64;
  f32x4 acc[8];
  #pragma unroll
  for (int t = 0; t < 8; ++t) acc[t] = (f32x4){0.f, 0.f, 0.f, 0.f};
  gemm_nt_core<128, 64, 4, 1>(hbf_in + (size_t)bm * 512,
                              Wbf + (size_t)bn * 512, ldsA, ldsB, acc);
  int tid = threadIdx.x, w = tid >> 6, lane = tid & 63, quad = lane >> 4, l15 = lane & 15;
  #pragma unroll
  for (int i = 0; i < 2; ++i) {
    #pragma unroll
    for (int j = 0; j < 4; ++j) {
      int m0 = bm + w * 32 + i * 16 + quad * 4;
      int o = bn + j * 16 + l15;
      f32x4 v = acc[i * 4 + j];
      #pragma unroll
      for (int r = 0; r < 4; ++r) {
        size_t idx = (size_t)(m0 + r) * 512 + o;
        float val = h32_in[idx] + DT_STEP * fast_tanh(v[r] + bias[o]);
        h32_out[idx] = val;
        hbf_out[idx] = f2bf(val);
      }
    }
  }
}

// ---------------- Proj + residual: out[b,o,s] = x[b,o,s] + pb[o] + W h ----------------
// A = projw[512,512], B = hbf[8192,512]. MB=64,NB=128, waves 1x4.
__global__ __launch_bounds__(256) void gemm_proj_mfma(
    const unsigned short* __restrict__ Wbf, const unsigned short* __restrict__ hbf,
    const float* __restrict__ pb, const float* __restrict__ x,
    float* __restrict__ Out) {
  __shared__ __align__(16) unsigned short ldsA[64 * 32];
  __shared__ __align__(16) unsigned short ldsB[128 * 32];
  int bn = blockIdx.x * 128, bm = blockIdx.y * 64;
  f32x4 acc[8];
  #pragma unroll
  for (int t = 0; t < 8; ++t) acc[t] = (f32x4){0.f, 0.f, 0.f, 0.f};
  gemm_nt_core<64, 128, 1, 4>(Wbf + (size_t)bm * 512,
                              hbf + (size_t)bn * 512, ldsA, ldsB, acc);
  int tid = threadIdx.x, w = tid >> 6, lane = tid & 63, quad = lane >> 4, l15 = lane & 15;
  #pragma unroll
  for (int i = 0; i < 4; ++i) {
    #pragma unroll
    for (int j = 0; j < 2; ++j) {
      int o0 = bm + i * 16 + quad * 4;
      int n = bn + w * 32 + j * 16 + l15;
      int b = n >> 10, s = n & 1023;
      f32x4 v = acc[i * 2 + j];
      #pragma unroll
      for (int r = 0; r < 4; ++r) {
        size_t idx = ((size_t)b * C_ + o0 + r) * S_ + s;
        Out[idx] = x[idx] + pb[o0 + r] + v[r];
      }
    }
  }
}

extern "C" void kernel_launch(void* const* d_in, const int* in_sizes, int n_in,
                              void* d_out, int out_size, void* d_ws, size_t ws_size,
                              hipStream_t stream) {
  const float* x        = (const float*)d_in[0];
  const float* gn_scale = (const float*)d_in[1];
  const float* gn_bias  = (const float*)d_in[2];
  const float* qkv_w    = (const float*)d_in[3];
  const float* qkv_b    = (const float*)d_in[4];
  const float* proj_w   = (const float*)d_in[5];
  const float* proj_b   = (const float*)d_in[6];
  const float* inl_w    = (const float*)d_in[7];
  const float* inl_b    = (const float*)d_in[8];
  float* out = (float*)d_out;
  float* ws = (float*)d_ws;

  // ws layout (float offsets):
  //   [0,4M)    A32 fp32 [8192,512]
  //   [4M,8M)   B32 fp32
  //   [8M,10M)  Qt bf16 [B,NH,S,HD]
  //   [10M,12M) Kt bf16
  //   [12M,14M) Vt bf16 [B,C,S]
  //   [14M,16M) h_t bf16 [B,S,C]  (reused as Bbf after QKV GEMM)
  //   [16M,18M) Abf bf16
  //   [18M,..)  bf16 weights
  float* A32 = ws;
  float* B32 = ws + 4194304;
  unsigned short* Qt  = (unsigned short*)(ws + 8388608);
  unsigned short* Kt  = (unsigned short*)(ws + 10485760);
  unsigned short* Vt  = (unsigned short*)(ws + 12582912);
  unsigned short* h_t = (unsigned short*)(ws + 14680064);
  unsigned short* Bbf = h_t;
  unsigned short* Abf = (unsigned short*)(ws + 16777216);
  unsigned short* qkvw_bf  = (unsigned short*)(ws + 18874368);
  unsigned short* inlw_bf  = qkvw_bf + 786432;
  unsigned short* projw_bf = inlw_bf + 262144;

  cast3_kernel<<<640, 256, 0, stream>>>(qkv_w, inl_w, proj_w, qkvw_bf, inlw_bf, projw_bf);
  groupnorm_t<<<64, 256, 0, stream>>>(x, gn_scale, gn_bias, h_t);
  gemm_qkv_mfma<<<dim3(8, 12, 8), 256, 0, stream>>>(qkvw_bf, h_t, qkv_b, Qt, Kt, Vt);
  attn_mfma<<<1024, 256, 0, stream>>>(Qt, Kt, Vt, A32, Abf);
  gemm_inl_mfma<<<dim3(8, 64), 256, 0, stream>>>(Abf, inlw_bf, inl_b, A32, B32, Bbf);
  gemm_inl_mfma<<<dim3(8, 64), 256, 0, stream>>>(Bbf, inlw_bf, inl_b, B32, A32, Abf);
  gemm_inl_mfma<<<dim3(8, 64), 256, 0, stream>>>(Abf, inlw_bf, inl_b, A32, B32, Bbf);
  gemm_proj_mfma<<<dim3(64, 8), 256, 0, stream>>>(projw_bf, Bbf, proj_b, x, out);
}

// Round 4
// 252.402 us; speedup vs baseline: 10.5537x; 1.0966x over previous
//
#include <hip/hip_runtime.h>
#include <math.h>

#define B_ 8
#define C_ 512
#define S_ 1024
#define HD 64
#define NHEADS 8
#define NGROUPS 8
#define DT_STEP 0.1f
#define EPS_GN 1e-5f

typedef __attribute__((ext_vector_type(8))) short bf16x8;
typedef __attribute__((ext_vector_type(4))) float f32x4;
typedef __attribute__((ext_vector_type(8))) unsigned short ushort8;
typedef __attribute__((ext_vector_type(4))) unsigned short ushort4_t;

static __device__ __forceinline__ unsigned short f2bf(float f) {
  unsigned int u = __builtin_bit_cast(unsigned int, f);
  u += 0x7fff + ((u >> 16) & 1);           // round-to-nearest-even
  return (unsigned short)(u >> 16);
}

static __device__ __forceinline__ float fast_tanh(float x) {
  float xc = fminf(fmaxf(x, -15.f), 15.f);
  float e = __expf(2.f * xc);
  return (e - 1.f) / (e + 1.f);
}

static __device__ __forceinline__ void load16_lds(const void* g, void* l) {
  __builtin_amdgcn_global_load_lds((const __attribute__((address_space(1))) void*)g,
                                   (__attribute__((address_space(3))) void*)l, 16, 0, 0);
}

// ---------------- cast fp32 weights -> bf16 ----------------
__global__ __launch_bounds__(256) void cast3_kernel(
    const float* __restrict__ a, const float* __restrict__ b, const float* __restrict__ c,
    unsigned short* __restrict__ A, unsigned short* __restrict__ B, unsigned short* __restrict__ C) {
  int bid = blockIdx.x;
  const float* src; unsigned short* dst; int off;
  if (bid < 384) { src = a; dst = A; off = bid * 2048; }
  else if (bid < 512) { src = b; dst = B; off = (bid - 384) * 2048; }
  else { src = c; dst = C; off = (bid - 512) * 2048; }
  int i = off + threadIdx.x * 8;
  f32x4 v0 = *(const f32x4*)(src + i);
  f32x4 v1 = *(const f32x4*)(src + i + 4);
  ushort8 o;
  o[0] = f2bf(v0[0]); o[1] = f2bf(v0[1]); o[2] = f2bf(v0[2]); o[3] = f2bf(v0[3]);
  o[4] = f2bf(v1[0]); o[5] = f2bf(v1[1]); o[6] = f2bf(v1[2]); o[7] = f2bf(v1[3]);
  *(ushort8*)(dst + i) = o;
}

// ---------------- GroupNorm + transpose: x[B,C,S] -> h_t[B,S,C] bf16 ----------------
__global__ __launch_bounds__(256) void groupnorm_t(
    const float* __restrict__ x, const float* __restrict__ scale,
    const float* __restrict__ bias, unsigned short* __restrict__ h_t) {
  int bg = blockIdx.x;                 // B*NGROUPS = 64
  int b = bg / NGROUPS, g = bg % NGROUPS;
  const int CPG = 64;
  const int GS = CPG * S_;             // 65536
  const float* xp = x + ((size_t)b * C_ + (size_t)g * CPG) * S_;
  int tid = threadIdx.x;
  float sum = 0.f, sumsq = 0.f;
  for (int i = tid * 4; i < GS; i += 1024) {
    f32x4 v = *(const f32x4*)(xp + i);
    sum += v[0] + v[1] + v[2] + v[3];
    sumsq += v[0]*v[0] + v[1]*v[1] + v[2]*v[2] + v[3]*v[3];
  }
  __shared__ float s1[256], s2[256];
  s1[tid] = sum; s2[tid] = sumsq;
  __syncthreads();
  for (int off = 128; off > 0; off >>= 1) {
    if (tid < off) { s1[tid] += s1[tid + off]; s2[tid] += s2[tid + off]; }
    __syncthreads();
  }
  float mean = s1[0] / (float)GS;
  float var = s2[0] / (float)GS - mean * mean;
  float inv = rsqrtf(var + EPS_GN);

  int sl = tid >> 2;                   // s within tile
  int cq = (tid & 3) * 16;             // c base within group
  float sA[16], sB[16];
  #pragma unroll
  for (int u = 0; u < 16; ++u) {
    float scv = scale[g * 64 + cq + u];
    sA[u] = inv * scv;
    sB[u] = bias[g * 64 + cq + u] - mean * inv * scv;
  }

  __shared__ float tile[64][65];
  for (int st = 0; st < 16; ++st) {
    __syncthreads();
    #pragma unroll
    for (int it = 0; it < 16; ++it) {
      int lin = it * 256 + tid;        // 4096 = 64c x 64s
      int c = lin >> 6, s = lin & 63;
      tile[c][s] = xp[(size_t)c * S_ + st * 64 + s];
    }
    __syncthreads();
    unsigned short vals[16];
    #pragma unroll
    for (int u = 0; u < 16; ++u)
      vals[u] = f2bf(tile[cq + u][sl] * sA[u] + sB[u]);
    unsigned short* dst = h_t + ((size_t)b * S_ + st * 64 + sl) * C_ + g * 64 + cq;
    ushort8 lo, hi;
    #pragma unroll
    for (int u = 0; u < 8; ++u) { lo[u] = vals[u]; hi[u] = vals[u + 8]; }
    *(ushort8*)dst = lo;
    *(ushort8*)(dst + 8) = hi;
  }
}

// ---------------- NT GEMM core: C[MB,NB] = A[MB,K=512] * B[NB,K=512]^T ----------------
template<int MB, int NB, int WMG, int WNG>
__device__ __forceinline__ void gemm_nt_core(
    const unsigned short* __restrict__ Ab,   // + bm*K
    const unsigned short* __restrict__ Bb,   // + bn*K
    unsigned short* ldsA, unsigned short* ldsB,
    f32x4* acc) {                            // [TI*TJ]
  constexpr int TI = (MB / WMG) / 16;
  constexpr int TJ = (NB / WNG) / 16;
  constexpr int NQA = MB * 4 / 256;
  constexpr int NQB = NB * 4 / 256;
  const int K = 512;
  const int tid = threadIdx.x;
  const int w = tid >> 6, lane = tid & 63, quad = lane >> 4, l15 = lane & 15;
  const int wm = (WNG == 1) ? w : ((WMG == 1) ? 0 : (w >> 1));
  const int wn = (WNG == 1) ? 0 : ((WMG == 1) ? w : (w & 1));

  for (int k0 = 0; k0 < K; k0 += 32) {
    __syncthreads();
    #pragma unroll
    for (int q = 0; q < NQA; ++q) {
      int c = q * 256 + tid;
      load16_lds(Ab + (size_t)(c >> 2) * K + k0 + (c & 3) * 8, ldsA + c * 8);
    }
    #pragma unroll
    for (int q = 0; q < NQB; ++q) {
      int c = q * 256 + tid;
      load16_lds(Bb + (size_t)(c >> 2) * K + k0 + (c & 3) * 8, ldsB + c * 8);
    }
    __syncthreads();
    bf16x8 af[TI], bf[TJ];
    #pragma unroll
    for (int i = 0; i < TI; ++i)
      af[i] = *(const bf16x8*)(ldsA + (wm * (MB / WMG) + i * 16 + l15) * 32 + quad * 8);
    #pragma unroll
    for (int j = 0; j < TJ; ++j)
      bf[j] = *(const bf16x8*)(ldsB + (wn * (NB / WNG) + j * 16 + l15) * 32 + quad * 8);
    #pragma unroll
    for (int i = 0; i < TI; ++i)
      #pragma unroll
      for (int j = 0; j < TJ; ++j)
        acc[i * TJ + j] = __builtin_amdgcn_mfma_f32_16x16x32_bf16(af[i], bf[j], acc[i * TJ + j], 0, 0, 0);
  }
}

// ---------------- QKV GEMM: W_bf[1536,512] x h_t[b][1024,512]^T ----------------
// Q pre-scaled by hd^-0.5 here so attention skips it.
__global__ __launch_bounds__(256) void gemm_qkv_mfma(
    const unsigned short* __restrict__ Wbf, const unsigned short* __restrict__ h_t,
    const float* __restrict__ bias,
    unsigned short* __restrict__ Qt, unsigned short* __restrict__ Kt,
    unsigned short* __restrict__ Vt) {
  __shared__ __align__(16) unsigned short ldsA[128 * 32];
  __shared__ __align__(16) unsigned short ldsB[128 * 32];
  int b = blockIdx.z;
  int bm = blockIdx.y * 128, bn = blockIdx.x * 128;
  f32x4 acc[16];
  #pragma unroll
  for (int t = 0; t < 16; ++t) acc[t] = (f32x4){0.f, 0.f, 0.f, 0.f};
  gemm_nt_core<128, 128, 2, 2>(Wbf + (size_t)bm * 512,
                               h_t + ((size_t)b * S_ + bn) * 512, ldsA, ldsB, acc);
  int tid = threadIdx.x, w = tid >> 6, lane = tid & 63, quad = lane >> 4, l15 = lane & 15;
  int wm = w >> 1, wn = w & 1;
  int tensor = bm >> 9;                 // block entirely inside one of Q/K/V
  float qscale = (tensor == 0) ? 0.125f : 1.0f;
  #pragma unroll
  for (int i = 0; i < 4; ++i) {
    #pragma unroll
    for (int j = 0; j < 4; ++j) {
      int m0 = bm + wm * 64 + i * 16 + quad * 4;
      int ng = bn + wn * 64 + j * 16 + l15;
      f32x4 v = acc[i * 4 + j];
      if (tensor < 2) {
        int head = (m0 >> 6) & 7, d0 = m0 & 63;
        ushort4_t pk;
        #pragma unroll
        for (int r = 0; r < 4; ++r) pk[r] = f2bf((v[r] + bias[m0 + r]) * qscale);
        unsigned short* dst = (tensor ? Kt : Qt) +
            (((size_t)(b * 8 + head) * S_ + ng) * 64 + d0);
        *(ushort4_t*)dst = pk;
      } else {
        #pragma unroll
        for (int r = 0; r < 4; ++r)
          Vt[(size_t)b * (C_ * S_) + (size_t)(m0 - 1024 + r) * S_ + ng] = f2bf(v[r] + bias[m0 + r]);
      }
    }
  }
}

// ---------------- Flash attention, bf16 MFMA, no-max softmax ----------------
// grid 1024: bid = sblk*64 + (b*8+n)  => all sblk of one (b,n) share an XCD
__global__ __launch_bounds__(256) void attn_mfma(
    const unsigned short* __restrict__ Qt,   // [B][NH][S][HD] (pre-scaled)
    const unsigned short* __restrict__ Kt,   // [B][NH][S][HD]
    const unsigned short* __restrict__ Vt,   // [B][C][S]
    float* __restrict__ hflat,               // [B][S][C] fp32
    unsigned short* __restrict__ hflat_bf) { // [B][S][C] bf16
  int tid = threadIdx.x, wave = tid >> 6, lane = tid & 63;
  int quad = lane >> 4, l15 = lane & 15;
  int bid = blockIdx.x;
  int bn = bid & 63, sblk = bid >> 6, b = bn >> 3, n = bn & 7;
  int s0w = sblk * 64 + wave * 16;

  __shared__ unsigned short k_lds[64][72];
  __shared__ unsigned short v_lds[64][72];
  __shared__ unsigned short p_lds[4][16][72];

  const unsigned short* Qb = Qt + (((size_t)(b * 8 + n)) * S_ + s0w + l15) * 64;
  const unsigned short* Kb = Kt + ((size_t)(b * 8 + n)) * S_ * 64;
  const unsigned short* Vb = Vt + ((size_t)b * C_ + n * 64) * S_;

  bf16x8 qa0 = *(const bf16x8*)(Qb + quad * 8);
  bf16x8 qa1 = *(const bf16x8*)(Qb + 32 + quad * 8);

  bf16x8 ones;
  #pragma unroll
  for (int j = 0; j < 8; ++j) ones[j] = (short)0x3F80;   // bf16 1.0

  f32x4 o_acc[4];
  f32x4 l_acc = {0.f, 0.f, 0.f, 0.f};
  #pragma unroll
  for (int dc = 0; dc < 4; ++dc) o_acc[dc] = (f32x4){0.f, 0.f, 0.f, 0.f};

  for (int t0 = 0; t0 < S_; t0 += 64) {
    __syncthreads();
    #pragma unroll
    for (int it = 0; it < 2; ++it) {
      int idx = tid + it * 256;
      int row = idx >> 3, c8 = (idx & 7) * 8;
      *(ushort8*)&k_lds[row][c8] = *(const ushort8*)(Kb + (size_t)(t0 + row) * 64 + c8);
      *(ushort8*)&v_lds[row][c8] = *(const ushort8*)(Vb + (size_t)row * S_ + t0 + c8);
    }
    __syncthreads();

    // QK^T (Q pre-scaled): s=(s0w+quad*4+r), t=(t0+tc*16+l15)
    f32x4 sc[4];
    #pragma unroll
    for (int tc = 0; tc < 4; ++tc) {
      bf16x8 kb0 = *(const bf16x8*)&k_lds[tc * 16 + l15][quad * 8];
      bf16x8 kb1 = *(const bf16x8*)&k_lds[tc * 16 + l15][32 + quad * 8];
      f32x4 c = {0.f, 0.f, 0.f, 0.f};
      c = __builtin_amdgcn_mfma_f32_16x16x32_bf16(qa0, kb0, c, 0, 0, 0);
      sc[tc] = __builtin_amdgcn_mfma_f32_16x16x32_bf16(qa1, kb1, c, 0, 0, 0);
    }

    // exp without max subtraction (scores |.| < ~15; fp32-safe), P -> LDS
    #pragma unroll
    for (int tc = 0; tc < 4; ++tc)
      #pragma unroll
      for (int r = 0; r < 4; ++r)
        p_lds[wave][quad * 4 + r][tc * 16 + l15] = f2bf(__expf(sc[tc][r]));

    bf16x8 pa0 = *(const bf16x8*)&p_lds[wave][l15][quad * 8];
    bf16x8 pa1 = *(const bf16x8*)&p_lds[wave][l15][32 + quad * 8];
    // row sums via ones-fragment MFMA (replicated across cols in C-layout)
    l_acc = __builtin_amdgcn_mfma_f32_16x16x32_bf16(pa0, ones, l_acc, 0, 0, 0);
    l_acc = __builtin_amdgcn_mfma_f32_16x16x32_bf16(pa1, ones, l_acc, 0, 0, 0);
    #pragma unroll
    for (int dc = 0; dc < 4; ++dc) {
      bf16x8 vb0 = *(const bf16x8*)&v_lds[dc * 16 + l15][quad * 8];
      bf16x8 vb1 = *(const bf16x8*)&v_lds[dc * 16 + l15][32 + quad * 8];
      o_acc[dc] = __builtin_amdgcn_mfma_f32_16x16x32_bf16(pa0, vb0, o_acc[dc], 0, 0, 0);
      o_acc[dc] = __builtin_amdgcn_mfma_f32_16x16x32_bf16(pa1, vb1, o_acc[dc], 0, 0, 0);
    }
  }

  float inv_l[4];
  #pragma unroll
  for (int r = 0; r < 4; ++r) inv_l[r] = 1.f / l_acc[r];
  #pragma unroll
  for (int dc = 0; dc < 4; ++dc) {
    #pragma unroll
    for (int r = 0; r < 4; ++r) {
      int s = s0w + quad * 4 + r;
      size_t idx = ((size_t)b * S_ + s) * C_ + n * 64 + dc * 16 + l15;
      float val = o_acc[dc][r] * inv_l[r];
      hflat[idx] = val;
      hflat_bf[idx] = f2bf(val);
    }
  }
}

// ---------------- INL step: h' = h + dt*tanh(h W^T + b) ----------------
__global__ __launch_bounds__(256) void gemm_inl_mfma(
    const unsigned short* __restrict__ hbf_in, const unsigned short* __restrict__ Wbf,
    const float* __restrict__ bias, const float* __restrict__ h32_in,
    float* __restrict__ h32_out, unsigned short* __restrict__ hbf_out) {
  __shared__ __align__(16) unsigned short ldsA[128 * 32];
  __shared__ __align__(16) unsigned short ldsB[64 * 32];
  int bm = blockIdx.y * 128, bn = blockIdx.x * 64;
  f32x4 acc[8];
  #pragma unroll
  for (int t = 0; t < 8; ++t) acc[t] = (f32x4){0.f, 0.f, 0.f, 0.f};
  gemm_nt_core<128, 64, 4, 1>(hbf_in + (size_t)bm * 512,
                              Wbf + (size_t)bn * 512, ldsA, ldsB, acc);
  int tid = threadIdx.x, w = tid >> 6, lane = tid & 63, quad = lane >> 4, l15 = lane & 15;
  #pragma unroll
  for (int i = 0; i < 2; ++i) {
    #pragma unroll
    for (int j = 0; j < 4; ++j) {
      int m0 = bm + w * 32 + i * 16 + quad * 4;
      int o = bn + j * 16 + l15;
      f32x4 v = acc[i * 4 + j];
      #pragma unroll
      for (int r = 0; r < 4; ++r) {
        size_t idx = (size_t)(m0 + r) * 512 + o;
        float val = h32_in[idx] + DT_STEP * fast_tanh(v[r] + bias[o]);
        h32_out[idx] = val;
        hbf_out[idx] = f2bf(val);
      }
    }
  }
}

// ---------------- Proj + residual ----------------
__global__ __launch_bounds__(256) void gemm_proj_mfma(
    const unsigned short* __restrict__ Wbf, const unsigned short* __restrict__ hbf,
    const float* __restrict__ pb, const float* __restrict__ x,
    float* __restrict__ Out) {
  __shared__ __align__(16) unsigned short ldsA[64 * 32];
  __shared__ __align__(16) unsigned short ldsB[128 * 32];
  int bn = blockIdx.x * 128, bm = blockIdx.y * 64;
  f32x4 acc[8];
  #pragma unroll
  for (int t = 0; t < 8; ++t) acc[t] = (f32x4){0.f, 0.f, 0.f, 0.f};
  gemm_nt_core<64, 128, 1, 4>(Wbf + (size_t)bm * 512,
                              hbf + (size_t)bn * 512, ldsA, ldsB, acc);
  int tid = threadIdx.x, w = tid >> 6, lane = tid & 63, quad = lane >> 4, l15 = lane & 15;
  #pragma unroll
  for (int i = 0; i < 4; ++i) {
    #pragma unroll
    for (int j = 0; j < 2; ++j) {
      int o0 = bm + i * 16 + quad * 4;
      int n = bn + w * 32 + j * 16 + l15;
      int b = n >> 10, s = n & 1023;
      f32x4 v = acc[i * 2 + j];
      #pragma unroll
      for (int r = 0; r < 4; ++r) {
        size_t idx = ((size_t)b * C_ + o0 + r) * S_ + s;
        Out[idx] = x[idx] + pb[o0 + r] + v[r];
      }
    }
  }
}

extern "C" void kernel_launch(void* const* d_in, const int* in_sizes, int n_in,
                              void* d_out, int out_size, void* d_ws, size_t ws_size,
                              hipStream_t stream) {
  const float* x        = (const float*)d_in[0];
  const float* gn_scale = (const float*)d_in[1];
  const float* gn_bias  = (const float*)d_in[2];
  const float* qkv_w    = (const float*)d_in[3];
  const float* qkv_b    = (const float*)d_in[4];
  const float* proj_w   = (const float*)d_in[5];
  const float* proj_b   = (const float*)d_in[6];
  const float* inl_w    = (const float*)d_in[7];
  const float* inl_b    = (const float*)d_in[8];
  float* out = (float*)d_out;
  float* ws = (float*)d_ws;

  float* A32 = ws;
  float* B32 = ws + 4194304;
  unsigned short* Qt  = (unsigned short*)(ws + 8388608);
  unsigned short* Kt  = (unsigned short*)(ws + 10485760);
  unsigned short* Vt  = (unsigned short*)(ws + 12582912);
  unsigned short* h_t = (unsigned short*)(ws + 14680064);
  unsigned short* Bbf = h_t;
  unsigned short* Abf = (unsigned short*)(ws + 16777216);
  unsigned short* qkvw_bf  = (unsigned short*)(ws + 18874368);
  unsigned short* inlw_bf  = qkvw_bf + 786432;
  unsigned short* projw_bf = inlw_bf + 262144;

  cast3_kernel<<<640, 256, 0, stream>>>(qkv_w, inl_w, proj_w, qkvw_bf, inlw_bf, projw_bf);
  groupnorm_t<<<64, 256, 0, stream>>>(x, gn_scale, gn_bias, h_t);
  gemm_qkv_mfma<<<dim3(8, 12, 8), 256, 0, stream>>>(qkvw_bf, h_t, qkv_b, Qt, Kt, Vt);
  attn_mfma<<<1024, 256, 0, stream>>>(Qt, Kt, Vt, A32, Abf);
  gemm_inl_mfma<<<dim3(8, 64), 256, 0, stream>>>(Abf, inlw_bf, inl_b, A32, B32, Bbf);
  gemm_inl_mfma<<<dim3(8, 64), 256, 0, stream>>>(Bbf, inlw_bf, inl_b, B32, A32, Abf);
  gemm_inl_mfma<<<dim3(8, 64), 256, 0, stream>>>(Abf, inlw_bf, inl_b, A32, B32, Bbf);
  gemm_proj_mfma<<<dim3(64, 8), 256, 0, stream>>>(projw_bf, Bbf, proj_b, x, out);
}

// Round 5
// 245.034 us; speedup vs baseline: 10.8710x; 1.0301x over previous
//
#include <hip/hip_runtime.h>
#include <math.h>

#define B_ 8
#define C_ 512
#define S_ 1024
#define HD 64
#define NHEADS 8
#define NGROUPS 8
#define DT_STEP 0.1f
#define EPS_GN 1e-5f

typedef __attribute__((ext_vector_type(8))) short bf16x8;
typedef __attribute__((ext_vector_type(4))) float f32x4;
typedef __attribute__((ext_vector_type(8))) unsigned short ushort8;
typedef __attribute__((ext_vector_type(4))) unsigned short ushort4_t;

static __device__ __forceinline__ unsigned short f2bf(float f) {
  unsigned int u = __builtin_bit_cast(unsigned int, f);
  u += 0x7fff + ((u >> 16) & 1);           // round-to-nearest-even
  return (unsigned short)(u >> 16);
}

static __device__ __forceinline__ float bf2f(unsigned short u) {
  unsigned int t = ((unsigned int)u) << 16;
  return __builtin_bit_cast(float, t);
}

static __device__ __forceinline__ float fast_tanh(float x) {
  float xc = fminf(fmaxf(x, -15.f), 15.f);
  float e = __expf(2.f * xc);
  return (e - 1.f) / (e + 1.f);
}

static __device__ __forceinline__ void load16_lds(const void* g, void* l) {
  __builtin_amdgcn_global_load_lds((const __attribute__((address_space(1))) void*)g,
                                   (__attribute__((address_space(3))) void*)l, 16, 0, 0);
}

// ---------------- cast fp32 weights -> bf16 ----------------
__global__ __launch_bounds__(256) void cast3_kernel(
    const float* __restrict__ a, const float* __restrict__ b, const float* __restrict__ c,
    unsigned short* __restrict__ A, unsigned short* __restrict__ B, unsigned short* __restrict__ C) {
  int bid = blockIdx.x;
  const float* src; unsigned short* dst; int off;
  if (bid < 384) { src = a; dst = A; off = bid * 2048; }
  else if (bid < 512) { src = b; dst = B; off = (bid - 384) * 2048; }
  else { src = c; dst = C; off = (bid - 512) * 2048; }
  int i = off + threadIdx.x * 8;
  f32x4 v0 = *(const f32x4*)(src + i);
  f32x4 v1 = *(const f32x4*)(src + i + 4);
  ushort8 o;
  o[0] = f2bf(v0[0]); o[1] = f2bf(v0[1]); o[2] = f2bf(v0[2]); o[3] = f2bf(v0[3]);
  o[4] = f2bf(v1[0]); o[5] = f2bf(v1[1]); o[6] = f2bf(v1[2]); o[7] = f2bf(v1[3]);
  *(ushort8*)(dst + i) = o;
}

// ---------------- GroupNorm pass 1: partial sums ----------------
// grid 512 = 64 (b,g) x 8 chunks; each block reduces 8192 floats
__global__ __launch_bounds__(256) void gn_stats(
    const float* __restrict__ x, float* __restrict__ gpart) {
  int bid = blockIdx.x;
  int bg = bid >> 3, chunk = bid & 7;
  const float* xp = x + (size_t)bg * 65536 + (size_t)chunk * 8192;
  int tid = threadIdx.x;
  float sum = 0.f, sq = 0.f;
  #pragma unroll
  for (int i = 0; i < 8; ++i) {
    f32x4 v = *(const f32x4*)(xp + i * 1024 + tid * 4);
    sum += v[0] + v[1] + v[2] + v[3];
    sq += v[0]*v[0] + v[1]*v[1] + v[2]*v[2] + v[3]*v[3];
  }
  #pragma unroll
  for (int off = 32; off >= 1; off >>= 1) {
    sum += __shfl_xor(sum, off, 64);
    sq  += __shfl_xor(sq, off, 64);
  }
  __shared__ float s1[4], s2[4];
  int wave = tid >> 6, lane = tid & 63;
  if (lane == 0) { s1[wave] = sum; s2[wave] = sq; }
  __syncthreads();
  if (tid == 0) {
    float S = s1[0] + s1[1] + s1[2] + s1[3];
    float Q = s2[0] + s2[1] + s2[2] + s2[3];
    gpart[bg * 16 + chunk * 2] = S;
    gpart[bg * 16 + chunk * 2 + 1] = Q;
  }
}

// ---------------- GroupNorm pass 2: normalize + transpose to h_t[B,S,C] bf16 ----------------
// grid 1024 = 64 (b,g) x 16 s-tiles
__global__ __launch_bounds__(256) void gn_apply_t(
    const float* __restrict__ x, const float* __restrict__ gpart,
    const float* __restrict__ scale, const float* __restrict__ bias,
    unsigned short* __restrict__ h_t) {
  int bid = blockIdx.x;
  int bg = bid >> 4, st = bid & 15;
  int b = bg >> 3, g = bg & 7;
  float S = 0.f, Q = 0.f;
  #pragma unroll
  for (int i = 0; i < 8; ++i) {
    S += gpart[bg * 16 + i * 2];
    Q += gpart[bg * 16 + i * 2 + 1];
  }
  float mean = S / 65536.f;
  float var = Q / 65536.f - mean * mean;
  float inv = rsqrtf(var + EPS_GN);

  int tid = threadIdx.x;
  int sl = tid >> 2;                   // s within tile
  int cq = (tid & 3) * 16;             // c base within group
  float sA[16], sB[16];
  #pragma unroll
  for (int u = 0; u < 16; ++u) {
    float scv = scale[g * 64 + cq + u];
    sA[u] = inv * scv;
    sB[u] = bias[g * 64 + cq + u] - mean * inv * scv;
  }

  const float* xp = x + ((size_t)b * C_ + (size_t)g * 64) * S_;
  __shared__ float tile[64][65];
  #pragma unroll
  for (int it = 0; it < 16; ++it) {
    int lin = it * 256 + tid;          // 4096 = 64c x 64s
    int c = lin >> 6, s = lin & 63;
    tile[c][s] = xp[(size_t)c * S_ + st * 64 + s];
  }
  __syncthreads();
  unsigned short vals[16];
  #pragma unroll
  for (int u = 0; u < 16; ++u)
    vals[u] = f2bf(tile[cq + u][sl] * sA[u] + sB[u]);
  unsigned short* dst = h_t + ((size_t)b * S_ + st * 64 + sl) * C_ + g * 64 + cq;
  ushort8 lo, hi;
  #pragma unroll
  for (int u = 0; u < 8; ++u) { lo[u] = vals[u]; hi[u] = vals[u + 8]; }
  *(ushort8*)dst = lo;
  *(ushort8*)(dst + 8) = hi;
}

// ---------------- NT GEMM core (for QKV): C[MB,NB] = A[MB,512] * B[NB,512]^T ----------------
template<int MB, int NB, int WMG, int WNG>
__device__ __forceinline__ void gemm_nt_core(
    const unsigned short* __restrict__ Ab,
    const unsigned short* __restrict__ Bb,
    unsigned short* ldsA, unsigned short* ldsB,
    f32x4* acc) {
  constexpr int TI = (MB / WMG) / 16;
  constexpr int TJ = (NB / WNG) / 16;
  constexpr int NQA = MB * 4 / 256;
  constexpr int NQB = NB * 4 / 256;
  const int K = 512;
  const int tid = threadIdx.x;
  const int w = tid >> 6, lane = tid & 63, quad = lane >> 4, l15 = lane & 15;
  const int wm = (WNG == 1) ? w : ((WMG == 1) ? 0 : (w >> 1));
  const int wn = (WNG == 1) ? 0 : ((WMG == 1) ? w : (w & 1));

  for (int k0 = 0; k0 < K; k0 += 32) {
    __syncthreads();
    #pragma unroll
    for (int q = 0; q < NQA; ++q) {
      int c = q * 256 + tid;
      load16_lds(Ab + (size_t)(c >> 2) * K + k0 + (c & 3) * 8, ldsA + c * 8);
    }
    #pragma unroll
    for (int q = 0; q < NQB; ++q) {
      int c = q * 256 + tid;
      load16_lds(Bb + (size_t)(c >> 2) * K + k0 + (c & 3) * 8, ldsB + c * 8);
    }
    __syncthreads();
    bf16x8 af[TI], bfr[TJ];
    #pragma unroll
    for (int i = 0; i < TI; ++i)
      af[i] = *(const bf16x8*)(ldsA + (wm * (MB / WMG) + i * 16 + l15) * 32 + quad * 8);
    #pragma unroll
    for (int j = 0; j < TJ; ++j)
      bfr[j] = *(const bf16x8*)(ldsB + (wn * (NB / WNG) + j * 16 + l15) * 32 + quad * 8);
    #pragma unroll
    for (int i = 0; i < TI; ++i)
      #pragma unroll
      for (int j = 0; j < TJ; ++j)
        acc[i * TJ + j] = __builtin_amdgcn_mfma_f32_16x16x32_bf16(af[i], bfr[j], acc[i * TJ + j], 0, 0, 0);
  }
}

// ---------------- QKV GEMM: W_bf[1536,512] x h_t[b][1024,512]^T ----------------
__global__ __launch_bounds__(256) void gemm_qkv_mfma(
    const unsigned short* __restrict__ Wbf, const unsigned short* __restrict__ h_t,
    const float* __restrict__ bias,
    unsigned short* __restrict__ Qt, unsigned short* __restrict__ Kt,
    unsigned short* __restrict__ Vt) {
  __shared__ __align__(16) unsigned short ldsA[128 * 32];
  __shared__ __align__(16) unsigned short ldsB[128 * 32];
  int b = blockIdx.z;
  int bm = blockIdx.y * 128, bn = blockIdx.x * 128;
  f32x4 acc[16];
  #pragma unroll
  for (int t = 0; t < 16; ++t) acc[t] = (f32x4){0.f, 0.f, 0.f, 0.f};
  gemm_nt_core<128, 128, 2, 2>(Wbf + (size_t)bm * 512,
                               h_t + ((size_t)b * S_ + bn) * 512, ldsA, ldsB, acc);
  int tid = threadIdx.x, w = tid >> 6, lane = tid & 63, quad = lane >> 4, l15 = lane & 15;
  int wm = w >> 1, wn = w & 1;
  int tensor = bm >> 9;
  float qscale = (tensor == 0) ? 0.125f : 1.0f;
  #pragma unroll
  for (int i = 0; i < 4; ++i) {
    #pragma unroll
    for (int j = 0; j < 4; ++j) {
      int m0 = bm + wm * 64 + i * 16 + quad * 4;
      int ng = bn + wn * 64 + j * 16 + l15;
      f32x4 v = acc[i * 4 + j];
      if (tensor < 2) {
        int head = (m0 >> 6) & 7, d0 = m0 & 63;
        ushort4_t pk;
        #pragma unroll
        for (int r = 0; r < 4; ++r) pk[r] = f2bf((v[r] + bias[m0 + r]) * qscale);
        unsigned short* dst = (tensor ? Kt : Qt) +
            (((size_t)(b * 8 + head) * S_ + ng) * 64 + d0);
        *(ushort4_t*)dst = pk;
      } else {
        #pragma unroll
        for (int r = 0; r < 4; ++r)
          Vt[(size_t)b * (C_ * S_) + (size_t)(m0 - 1024 + r) * S_ + ng] = f2bf(v[r] + bias[m0 + r]);
      }
    }
  }
}

// ---------------- Flash attention, bf16 MFMA, no-max softmax ----------------
__global__ __launch_bounds__(256) void attn_mfma(
    const unsigned short* __restrict__ Qt,   // [B][NH][S][HD] (pre-scaled)
    const unsigned short* __restrict__ Kt,
    const unsigned short* __restrict__ Vt,   // [B][C][S]
    float* __restrict__ hflat) {             // [B][S][C] fp32
  int tid = threadIdx.x, wave = tid >> 6, lane = tid & 63;
  int quad = lane >> 4, l15 = lane & 15;
  int bid = blockIdx.x;
  int bn = bid & 63, sblk = bid >> 6, b = bn >> 3, n = bn & 7;
  int s0w = sblk * 64 + wave * 16;

  __shared__ unsigned short k_lds[64][72];
  __shared__ unsigned short v_lds[64][72];
  __shared__ unsigned short p_lds[4][16][72];

  const unsigned short* Qb = Qt + (((size_t)(b * 8 + n)) * S_ + s0w + l15) * 64;
  const unsigned short* Kb = Kt + ((size_t)(b * 8 + n)) * S_ * 64;
  const unsigned short* Vb = Vt + ((size_t)b * C_ + n * 64) * S_;

  bf16x8 qa0 = *(const bf16x8*)(Qb + quad * 8);
  bf16x8 qa1 = *(const bf16x8*)(Qb + 32 + quad * 8);

  bf16x8 ones;
  #pragma unroll
  for (int j = 0; j < 8; ++j) ones[j] = (short)0x3F80;

  f32x4 o_acc[4];
  f32x4 l_acc = {0.f, 0.f, 0.f, 0.f};
  #pragma unroll
  for (int dc = 0; dc < 4; ++dc) o_acc[dc] = (f32x4){0.f, 0.f, 0.f, 0.f};

  for (int t0 = 0; t0 < S_; t0 += 64) {
    __syncthreads();
    #pragma unroll
    for (int it = 0; it < 2; ++it) {
      int idx = tid + it * 256;
      int row = idx >> 3, c8 = (idx & 7) * 8;
      *(ushort8*)&k_lds[row][c8] = *(const ushort8*)(Kb + (size_t)(t0 + row) * 64 + c8);
      *(ushort8*)&v_lds[row][c8] = *(const ushort8*)(Vb + (size_t)row * S_ + t0 + c8);
    }
    __syncthreads();

    f32x4 sc[4];
    #pragma unroll
    for (int tc = 0; tc < 4; ++tc) {
      bf16x8 kb0 = *(const bf16x8*)&k_lds[tc * 16 + l15][quad * 8];
      bf16x8 kb1 = *(const bf16x8*)&k_lds[tc * 16 + l15][32 + quad * 8];
      f32x4 c = {0.f, 0.f, 0.f, 0.f};
      c = __builtin_amdgcn_mfma_f32_16x16x32_bf16(qa0, kb0, c, 0, 0, 0);
      sc[tc] = __builtin_amdgcn_mfma_f32_16x16x32_bf16(qa1, kb1, c, 0, 0, 0);
    }

    #pragma unroll
    for (int tc = 0; tc < 4; ++tc)
      #pragma unroll
      for (int r = 0; r < 4; ++r)
        p_lds[wave][quad * 4 + r][tc * 16 + l15] = f2bf(__expf(sc[tc][r]));

    bf16x8 pa0 = *(const bf16x8*)&p_lds[wave][l15][quad * 8];
    bf16x8 pa1 = *(const bf16x8*)&p_lds[wave][l15][32 + quad * 8];
    l_acc = __builtin_amdgcn_mfma_f32_16x16x32_bf16(pa0, ones, l_acc, 0, 0, 0);
    l_acc = __builtin_amdgcn_mfma_f32_16x16x32_bf16(pa1, ones, l_acc, 0, 0, 0);
    #pragma unroll
    for (int dc = 0; dc < 4; ++dc) {
      bf16x8 vb0 = *(const bf16x8*)&v_lds[dc * 16 + l15][quad * 8];
      bf16x8 vb1 = *(const bf16x8*)&v_lds[dc * 16 + l15][32 + quad * 8];
      o_acc[dc] = __builtin_amdgcn_mfma_f32_16x16x32_bf16(pa0, vb0, o_acc[dc], 0, 0, 0);
      o_acc[dc] = __builtin_amdgcn_mfma_f32_16x16x32_bf16(pa1, vb1, o_acc[dc], 0, 0, 0);
    }
  }

  float inv_l[4];
  #pragma unroll
  for (int r = 0; r < 4; ++r) inv_l[r] = 1.f / l_acc[r];
  #pragma unroll
  for (int dc = 0; dc < 4; ++dc) {
    #pragma unroll
    for (int r = 0; r < 4; ++r) {
      int s = s0w + quad * 4 + r;
      hflat[((size_t)b * S_ + s) * C_ + n * 64 + dc * 16 + l15] = o_acc[dc][r] * inv_l[r];
    }
  }
}

// ---------------- Fused 3x INL + proj ----------------
// Row-local: block owns 32 s-rows entirely in LDS. W streamed from L2.
// GEMM: A = W rows (m=o), B = h rows (n=s); C row=o, col=s.
static __device__ __forceinline__ void fused_gemm(
    const unsigned short* __restrict__ W,       // [512][512] bf16, o-major
    const unsigned short h_bf[32][520],
    int wave, int quad, int l15, f32x4 acc[16]) {
  const unsigned short* Wp = W + ((size_t)(wave * 128 + l15)) * 512 + quad * 8;
  #pragma unroll 4
  for (int k0 = 0; k0 < 512; k0 += 32) {
    bf16x8 b0 = *(const bf16x8*)&h_bf[l15][k0 + quad * 8];
    bf16x8 b1 = *(const bf16x8*)&h_bf[16 + l15][k0 + quad * 8];
    #pragma unroll
    for (int oi = 0; oi < 8; ++oi) {
      bf16x8 af = *(const bf16x8*)(Wp + (size_t)oi * 16 * 512 + k0);
      acc[oi * 2]     = __builtin_amdgcn_mfma_f32_16x16x32_bf16(af, b0, acc[oi * 2], 0, 0, 0);
      acc[oi * 2 + 1] = __builtin_amdgcn_mfma_f32_16x16x32_bf16(af, b1, acc[oi * 2 + 1], 0, 0, 0);
    }
  }
}

__global__ __launch_bounds__(256, 1) void inl3_proj_fused(
    const float* __restrict__ h_in,            // [B,S,C] fp32 (attn out)
    const unsigned short* __restrict__ Winl,   // [512][512] bf16
    const float* __restrict__ inl_bias,
    const unsigned short* __restrict__ Wproj,  // [512][512] bf16
    const float* __restrict__ proj_bias,
    const float* __restrict__ x,               // [B,C,S] fp32
    float* __restrict__ out) {                 // [B,C,S] fp32
  __shared__ float h32[32][512];
  __shared__ unsigned short h_bf[32][520];
  __shared__ unsigned short delta[32][520];
  __shared__ float bias_lds[512];

  int tid = threadIdx.x, wave = tid >> 6, lane = tid & 63;
  int quad = lane >> 4, l15 = lane & 15;
  int bid = blockIdx.x;
  int b = bid >> 5, s0 = (bid & 31) * 32;

  // init: load 32x512 fp32 rows, build bf16 copy
  const float* src = h_in + ((size_t)b * S_ + s0) * 512;
  #pragma unroll
  for (int u = 0; u < 8; ++u) {
    int idx = u * 2048 + tid * 8;
    int s = idx >> 9, c = idx & 511;
    f32x4 v0 = *(const f32x4*)(src + idx);
    f32x4 v1 = *(const f32x4*)(src + idx + 4);
    *(f32x4*)&h32[s][c] = v0;
    *(f32x4*)&h32[s][c + 4] = v1;
    ushort8 hb;
    #pragma unroll
    for (int j = 0; j < 4; ++j) { hb[j] = f2bf(v0[j]); hb[4 + j] = f2bf(v1[j]); }
    *(ushort8*)&h_bf[s][c] = hb;
  }
  if (tid < 128) *(f32x4*)&bias_lds[tid * 4] = *(const f32x4*)(inl_bias + tid * 4);
  __syncthreads();

  for (int it = 0; it < 3; ++it) {
    f32x4 acc[16];
    #pragma unroll
    for (int t = 0; t < 16; ++t) acc[t] = (f32x4){0.f, 0.f, 0.f, 0.f};
    fused_gemm(Winl, h_bf, wave, quad, l15, acc);
    // tanh -> delta (bf16)
    #pragma unroll
    for (int oi = 0; oi < 8; ++oi) {
      int o0 = wave * 128 + oi * 16 + quad * 4;
      #pragma unroll
      for (int sj = 0; sj < 2; ++sj) {
        f32x4 a = acc[oi * 2 + sj];
        ushort4_t d;
        #pragma unroll
        for (int r = 0; r < 4; ++r) d[r] = f2bf(fast_tanh(a[r] + bias_lds[o0 + r]));
        *(ushort4_t*)&delta[sj * 16 + l15][o0] = d;
      }
    }
    __syncthreads();
    // h += dt * delta (fp32 master), refresh bf16 copy
    #pragma unroll
    for (int u = 0; u < 8; ++u) {
      int idx = u * 2048 + tid * 8;
      int s = idx >> 9, c = idx & 511;
      ushort8 dv = *(ushort8*)&delta[s][c];
      f32x4 h0 = *(f32x4*)&h32[s][c];
      f32x4 h1 = *(f32x4*)&h32[s][c + 4];
      #pragma unroll
      for (int j = 0; j < 4; ++j) {
        h0[j] += DT_STEP * bf2f(dv[j]);
        h1[j] += DT_STEP * bf2f(dv[4 + j]);
      }
      *(f32x4*)&h32[s][c] = h0;
      *(f32x4*)&h32[s][c + 4] = h1;
      ushort8 hb;
      #pragma unroll
      for (int j = 0; j < 4; ++j) { hb[j] = f2bf(h0[j]); hb[4 + j] = f2bf(h1[j]); }
      *(ushort8*)&h_bf[s][c] = hb;
    }
    __syncthreads();
  }

  // proj
  if (tid < 128) *(f32x4*)&bias_lds[tid * 4] = *(const f32x4*)(proj_bias + tid * 4);
  __syncthreads();
  f32x4 acc[16];
  #pragma unroll
  for (int t = 0; t < 16; ++t) acc[t] = (f32x4){0.f, 0.f, 0.f, 0.f};
  fused_gemm(Wproj, h_bf, wave, quad, l15, acc);
  #pragma unroll
  for (int oi = 0; oi < 8; ++oi) {
    int o0 = wave * 128 + oi * 16 + quad * 4;
    #pragma unroll
    for (int sj = 0; sj < 2; ++sj) {
      int sg = s0 + sj * 16 + l15;
      f32x4 a = acc[oi * 2 + sj];
      #pragma unroll
      for (int r = 0; r < 4; ++r) {
        size_t idx = ((size_t)b * C_ + o0 + r) * S_ + sg;
        out[idx] = x[idx] + bias_lds[o0 + r] + a[r];
      }
    }
  }
}

extern "C" void kernel_launch(void* const* d_in, const int* in_sizes, int n_in,
                              void* d_out, int out_size, void* d_ws, size_t ws_size,
                              hipStream_t stream) {
  const float* x        = (const float*)d_in[0];
  const float* gn_scale = (const float*)d_in[1];
  const float* gn_bias  = (const float*)d_in[2];
  const float* qkv_w    = (const float*)d_in[3];
  const float* qkv_b    = (const float*)d_in[4];
  const float* proj_w   = (const float*)d_in[5];
  const float* proj_b   = (const float*)d_in[6];
  const float* inl_w    = (const float*)d_in[7];
  const float* inl_b    = (const float*)d_in[8];
  float* out = (float*)d_out;
  float* ws = (float*)d_ws;

  // ws layout (float offsets):
  //   [0,4M)        A32 fp32 [B,S,C] (attn out)
  //   [4M,+1K)      gpart (64 x 8 x 2)
  //   [8M,10M)      Qt bf16, [10M,12M) Kt bf16, [12M,14M) Vt bf16
  //   [14M,16M)     h_t bf16 [B,S,C]
  //   [18M,..)      bf16 weights
  float* A32 = ws;
  float* gpart = ws + 4194304;
  unsigned short* Qt  = (unsigned short*)(ws + 8388608);
  unsigned short* Kt  = (unsigned short*)(ws + 10485760);
  unsigned short* Vt  = (unsigned short*)(ws + 12582912);
  unsigned short* h_t = (unsigned short*)(ws + 14680064);
  unsigned short* qkvw_bf  = (unsigned short*)(ws + 18874368);
  unsigned short* inlw_bf  = qkvw_bf + 786432;
  unsigned short* projw_bf = inlw_bf + 262144;

  cast3_kernel<<<640, 256, 0, stream>>>(qkv_w, inl_w, proj_w, qkvw_bf, inlw_bf, projw_bf);
  gn_stats<<<512, 256, 0, stream>>>(x, gpart);
  gn_apply_t<<<1024, 256, 0, stream>>>(x, gpart, gn_scale, gn_bias, h_t);
  gemm_qkv_mfma<<<dim3(8, 12, 8), 256, 0, stream>>>(qkvw_bf, h_t, qkv_b, Qt, Kt, Vt);
  attn_mfma<<<1024, 256, 0, stream>>>(Qt, Kt, Vt, A32);
  inl3_proj_fused<<<256, 256, 0, stream>>>(A32, inlw_bf, inl_b, projw_bf, proj_b, x, out);
}

// Round 6
// 224.645 us; speedup vs baseline: 11.8577x; 1.0908x over previous
//
#include <hip/hip_runtime.h>
#include <math.h>

#define B_ 8
#define C_ 512
#define S_ 1024
#define HD 64
#define NHEADS 8
#define NGROUPS 8
#define DT_STEP 0.1f
#define EPS_GN 1e-5f

typedef __attribute__((ext_vector_type(8))) short bf16x8;
typedef __attribute__((ext_vector_type(4))) float f32x4;
typedef __attribute__((ext_vector_type(8))) unsigned short ushort8;
typedef __attribute__((ext_vector_type(4))) unsigned short ushort4_t;

static __device__ __forceinline__ unsigned short f2bf(float f) {
  unsigned int u = __builtin_bit_cast(unsigned int, f);
  u += 0x7fff + ((u >> 16) & 1);           // round-to-nearest-even
  return (unsigned short)(u >> 16);
}

static __device__ __forceinline__ float fast_tanh(float x) {
  float xc = fminf(fmaxf(x, -15.f), 15.f);
  float e = __expf(2.f * xc);
  return (e - 1.f) / (e + 1.f);
}

static __device__ __forceinline__ void load16_lds(const void* g, void* l) {
  __builtin_amdgcn_global_load_lds((const __attribute__((address_space(1))) void*)g,
                                   (__attribute__((address_space(3))) void*)l, 16, 0, 0);
}

// ---------------- cast fp32 weights -> bf16 ----------------
__global__ __launch_bounds__(256) void cast3_kernel(
    const float* __restrict__ a, const float* __restrict__ b, const float* __restrict__ c,
    unsigned short* __restrict__ A, unsigned short* __restrict__ B, unsigned short* __restrict__ C) {
  int bid = blockIdx.x;
  const float* src; unsigned short* dst; int off;
  if (bid < 384) { src = a; dst = A; off = bid * 2048; }
  else if (bid < 512) { src = b; dst = B; off = (bid - 384) * 2048; }
  else { src = c; dst = C; off = (bid - 512) * 2048; }
  int i = off + threadIdx.x * 8;
  f32x4 v0 = *(const f32x4*)(src + i);
  f32x4 v1 = *(const f32x4*)(src + i + 4);
  ushort8 o;
  o[0] = f2bf(v0[0]); o[1] = f2bf(v0[1]); o[2] = f2bf(v0[2]); o[3] = f2bf(v0[3]);
  o[4] = f2bf(v1[0]); o[5] = f2bf(v1[1]); o[6] = f2bf(v1[2]); o[7] = f2bf(v1[3]);
  *(ushort8*)(dst + i) = o;
}

// ---------------- GroupNorm pass 1: partial sums ----------------
__global__ __launch_bounds__(256) void gn_stats(
    const float* __restrict__ x, float* __restrict__ gpart) {
  int bid = blockIdx.x;
  int bg = bid >> 3, chunk = bid & 7;
  const float* xp = x + (size_t)bg * 65536 + (size_t)chunk * 8192;
  int tid = threadIdx.x;
  float sum = 0.f, sq = 0.f;
  #pragma unroll
  for (int i = 0; i < 8; ++i) {
    f32x4 v = *(const f32x4*)(xp + i * 1024 + tid * 4);
    sum += v[0] + v[1] + v[2] + v[3];
    sq += v[0]*v[0] + v[1]*v[1] + v[2]*v[2] + v[3]*v[3];
  }
  #pragma unroll
  for (int off = 32; off >= 1; off >>= 1) {
    sum += __shfl_xor(sum, off, 64);
    sq  += __shfl_xor(sq, off, 64);
  }
  __shared__ float s1[4], s2[4];
  int wave = tid >> 6, lane = tid & 63;
  if (lane == 0) { s1[wave] = sum; s2[wave] = sq; }
  __syncthreads();
  if (tid == 0) {
    float S = s1[0] + s1[1] + s1[2] + s1[3];
    float Q = s2[0] + s2[1] + s2[2] + s2[3];
    gpart[bg * 16 + chunk * 2] = S;
    gpart[bg * 16 + chunk * 2 + 1] = Q;
  }
}

// ---------------- GroupNorm pass 2: normalize + transpose to h_t[B,S,C] bf16 ----------------
__global__ __launch_bounds__(256) void gn_apply_t(
    const float* __restrict__ x, const float* __restrict__ gpart,
    const float* __restrict__ scale, const float* __restrict__ bias,
    unsigned short* __restrict__ h_t) {
  int bid = blockIdx.x;
  int bg = bid >> 4, st = bid & 15;
  int b = bg >> 3, g = bg & 7;
  float S = 0.f, Q = 0.f;
  #pragma unroll
  for (int i = 0; i < 8; ++i) {
    S += gpart[bg * 16 + i * 2];
    Q += gpart[bg * 16 + i * 2 + 1];
  }
  float mean = S / 65536.f;
  float var = Q / 65536.f - mean * mean;
  float inv = rsqrtf(var + EPS_GN);

  int tid = threadIdx.x;
  int sl = tid >> 2;
  int cq = (tid & 3) * 16;
  float sA[16], sB[16];
  #pragma unroll
  for (int u = 0; u < 16; ++u) {
    float scv = scale[g * 64 + cq + u];
    sA[u] = inv * scv;
    sB[u] = bias[g * 64 + cq + u] - mean * inv * scv;
  }

  const float* xp = x + ((size_t)b * C_ + (size_t)g * 64) * S_;
  __shared__ float tile[64][65];
  #pragma unroll
  for (int it = 0; it < 16; ++it) {
    int lin = it * 256 + tid;
    int c = lin >> 6, s = lin & 63;
    tile[c][s] = xp[(size_t)c * S_ + st * 64 + s];
  }
  __syncthreads();
  unsigned short vals[16];
  #pragma unroll
  for (int u = 0; u < 16; ++u)
    vals[u] = f2bf(tile[cq + u][sl] * sA[u] + sB[u]);
  unsigned short* dst = h_t + ((size_t)b * S_ + st * 64 + sl) * C_ + g * 64 + cq;
  ushort8 lo, hi;
  #pragma unroll
  for (int u = 0; u < 8; ++u) { lo[u] = vals[u]; hi[u] = vals[u + 8]; }
  *(ushort8*)dst = lo;
  *(ushort8*)(dst + 8) = hi;
}

// ---------------- NT GEMM core (for QKV): C[MB,NB] = A[MB,512] * B[NB,512]^T ----------------
template<int MB, int NB, int WMG, int WNG>
__device__ __forceinline__ void gemm_nt_core(
    const unsigned short* __restrict__ Ab,
    const unsigned short* __restrict__ Bb,
    unsigned short* ldsA, unsigned short* ldsB,
    f32x4* acc) {
  constexpr int TI = (MB / WMG) / 16;
  constexpr int TJ = (NB / WNG) / 16;
  constexpr int NQA = MB * 4 / 256;
  constexpr int NQB = NB * 4 / 256;
  const int K = 512;
  const int tid = threadIdx.x;
  const int w = tid >> 6, lane = tid & 63, quad = lane >> 4, l15 = lane & 15;
  const int wm = (WNG == 1) ? w : ((WMG == 1) ? 0 : (w >> 1));
  const int wn = (WNG == 1) ? 0 : ((WMG == 1) ? w : (w & 1));

  for (int k0 = 0; k0 < K; k0 += 32) {
    __syncthreads();
    #pragma unroll
    for (int q = 0; q < NQA; ++q) {
      int c = q * 256 + tid;
      load16_lds(Ab + (size_t)(c >> 2) * K + k0 + (c & 3) * 8, ldsA + c * 8);
    }
    #pragma unroll
    for (int q = 0; q < NQB; ++q) {
      int c = q * 256 + tid;
      load16_lds(Bb + (size_t)(c >> 2) * K + k0 + (c & 3) * 8, ldsB + c * 8);
    }
    __syncthreads();
    bf16x8 af[TI], bfr[TJ];
    #pragma unroll
    for (int i = 0; i < TI; ++i)
      af[i] = *(const bf16x8*)(ldsA + (wm * (MB / WMG) + i * 16 + l15) * 32 + quad * 8);
    #pragma unroll
    for (int j = 0; j < TJ; ++j)
      bfr[j] = *(const bf16x8*)(ldsB + (wn * (NB / WNG) + j * 16 + l15) * 32 + quad * 8);
    #pragma unroll
    for (int i = 0; i < TI; ++i)
      #pragma unroll
      for (int j = 0; j < TJ; ++j)
        acc[i * TJ + j] = __builtin_amdgcn_mfma_f32_16x16x32_bf16(af[i], bfr[j], acc[i * TJ + j], 0, 0, 0);
  }
}

// ---------------- QKV GEMM: W_bf[1536,512] x h_t[b][1024,512]^T ----------------
__global__ __launch_bounds__(256) void gemm_qkv_mfma(
    const unsigned short* __restrict__ Wbf, const unsigned short* __restrict__ h_t,
    const float* __restrict__ bias,
    unsigned short* __restrict__ Qt, unsigned short* __restrict__ Kt,
    unsigned short* __restrict__ Vt) {
  __shared__ __align__(16) unsigned short ldsA[128 * 32];
  __shared__ __align__(16) unsigned short ldsB[128 * 32];
  int b = blockIdx.z;
  int bm = blockIdx.y * 128, bn = blockIdx.x * 128;
  f32x4 acc[16];
  #pragma unroll
  for (int t = 0; t < 16; ++t) acc[t] = (f32x4){0.f, 0.f, 0.f, 0.f};
  gemm_nt_core<128, 128, 2, 2>(Wbf + (size_t)bm * 512,
                               h_t + ((size_t)b * S_ + bn) * 512, ldsA, ldsB, acc);
  int tid = threadIdx.x, w = tid >> 6, lane = tid & 63, quad = lane >> 4, l15 = lane & 15;
  int wm = w >> 1, wn = w & 1;
  int tensor = bm >> 9;
  float qscale = (tensor == 0) ? 0.125f : 1.0f;
  #pragma unroll
  for (int i = 0; i < 4; ++i) {
    #pragma unroll
    for (int j = 0; j < 4; ++j) {
      int m0 = bm + wm * 64 + i * 16 + quad * 4;
      int ng = bn + wn * 64 + j * 16 + l15;
      f32x4 v = acc[i * 4 + j];
      if (tensor < 2) {
        int head = (m0 >> 6) & 7, d0 = m0 & 63;
        ushort4_t pk;
        #pragma unroll
        for (int r = 0; r < 4; ++r) pk[r] = f2bf((v[r] + bias[m0 + r]) * qscale);
        unsigned short* dst = (tensor ? Kt : Qt) +
            (((size_t)(b * 8 + head) * S_ + ng) * 64 + d0);
        *(ushort4_t*)dst = pk;
      } else {
        #pragma unroll
        for (int r = 0; r < 4; ++r)
          Vt[(size_t)b * (C_ * S_) + (size_t)(m0 - 1024 + r) * S_ + ng] = f2bf(v[r] + bias[m0 + r]);
      }
    }
  }
}

// ---------------- Flash attention, bf16 MFMA, no-max softmax ----------------
__global__ __launch_bounds__(256) void attn_mfma(
    const unsigned short* __restrict__ Qt,   // [B][NH][S][HD] (pre-scaled)
    const unsigned short* __restrict__ Kt,
    const unsigned short* __restrict__ Vt,   // [B][C][S]
    float* __restrict__ hflat) {             // [B][S][C] fp32
  int tid = threadIdx.x, wave = tid >> 6, lane = tid & 63;
  int quad = lane >> 4, l15 = lane & 15;
  int bid = blockIdx.x;
  int bn = bid & 63, sblk = bid >> 6, b = bn >> 3, n = bn & 7;
  int s0w = sblk * 64 + wave * 16;

  __shared__ unsigned short k_lds[64][72];
  __shared__ unsigned short v_lds[64][72];
  __shared__ unsigned short p_lds[4][16][72];

  const unsigned short* Qb = Qt + (((size_t)(b * 8 + n)) * S_ + s0w + l15) * 64;
  const unsigned short* Kb = Kt + ((size_t)(b * 8 + n)) * S_ * 64;
  const unsigned short* Vb = Vt + ((size_t)b * C_ + n * 64) * S_;

  bf16x8 qa0 = *(const bf16x8*)(Qb + quad * 8);
  bf16x8 qa1 = *(const bf16x8*)(Qb + 32 + quad * 8);

  bf16x8 ones;
  #pragma unroll
  for (int j = 0; j < 8; ++j) ones[j] = (short)0x3F80;

  f32x4 o_acc[4];
  f32x4 l_acc = {0.f, 0.f, 0.f, 0.f};
  #pragma unroll
  for (int dc = 0; dc < 4; ++dc) o_acc[dc] = (f32x4){0.f, 0.f, 0.f, 0.f};

  for (int t0 = 0; t0 < S_; t0 += 64) {
    __syncthreads();
    #pragma unroll
    for (int it = 0; it < 2; ++it) {
      int idx = tid + it * 256;
      int row = idx >> 3, c8 = (idx & 7) * 8;
      *(ushort8*)&k_lds[row][c8] = *(const ushort8*)(Kb + (size_t)(t0 + row) * 64 + c8);
      *(ushort8*)&v_lds[row][c8] = *(const ushort8*)(Vb + (size_t)row * S_ + t0 + c8);
    }
    __syncthreads();

    f32x4 sc[4];
    #pragma unroll
    for (int tc = 0; tc < 4; ++tc) {
      bf16x8 kb0 = *(const bf16x8*)&k_lds[tc * 16 + l15][quad * 8];
      bf16x8 kb1 = *(const bf16x8*)&k_lds[tc * 16 + l15][32 + quad * 8];
      f32x4 c = {0.f, 0.f, 0.f, 0.f};
      c = __builtin_amdgcn_mfma_f32_16x16x32_bf16(qa0, kb0, c, 0, 0, 0);
      sc[tc] = __builtin_amdgcn_mfma_f32_16x16x32_bf16(qa1, kb1, c, 0, 0, 0);
    }

    #pragma unroll
    for (int tc = 0; tc < 4; ++tc)
      #pragma unroll
      for (int r = 0; r < 4; ++r)
        p_lds[wave][quad * 4 + r][tc * 16 + l15] = f2bf(__expf(sc[tc][r]));

    bf16x8 pa0 = *(const bf16x8*)&p_lds[wave][l15][quad * 8];
    bf16x8 pa1 = *(const bf16x8*)&p_lds[wave][l15][32 + quad * 8];
    l_acc = __builtin_amdgcn_mfma_f32_16x16x32_bf16(pa0, ones, l_acc, 0, 0, 0);
    l_acc = __builtin_amdgcn_mfma_f32_16x16x32_bf16(pa1, ones, l_acc, 0, 0, 0);
    #pragma unroll
    for (int dc = 0; dc < 4; ++dc) {
      bf16x8 vb0 = *(const bf16x8*)&v_lds[dc * 16 + l15][quad * 8];
      bf16x8 vb1 = *(const bf16x8*)&v_lds[dc * 16 + l15][32 + quad * 8];
      o_acc[dc] = __builtin_amdgcn_mfma_f32_16x16x32_bf16(pa0, vb0, o_acc[dc], 0, 0, 0);
      o_acc[dc] = __builtin_amdgcn_mfma_f32_16x16x32_bf16(pa1, vb1, o_acc[dc], 0, 0, 0);
    }
  }

  float inv_l[4];
  #pragma unroll
  for (int r = 0; r < 4; ++r) inv_l[r] = 1.f / l_acc[r];
  #pragma unroll
  for (int dc = 0; dc < 4; ++dc) {
    #pragma unroll
    for (int r = 0; r < 4; ++r) {
      int s = s0w + quad * 4 + r;
      hflat[((size_t)b * S_ + s) * C_ + n * 64 + dc * 16 + l15] = o_acc[dc][r] * inv_l[r];
    }
  }
}

// ---------------- Fused 3x INL + proj, W staged via async DMA double-buffer ----------------
// Block owns 32 s-rows. fp32 h master lives in REGISTERS mirroring the MFMA
// C-layout: thread owns (s = sj*16+l15, c = wave*128+oi*16+quad*4+r).
// Per k-step the 512x32 W slab (32 KB) is DMA'd into LDS buf cur^1 while
// MFMAs consume buf cur; the loop-top barrier's vmcnt drain is the pipeline wait.
__device__ __forceinline__ void stage_w32(const unsigned short* __restrict__ W,
                                          int k0, unsigned short* buf, int tid) {
  #pragma unroll
  for (int it = 0; it < 8; ++it) {
    int c = it * 256 + tid;
    load16_lds(W + (size_t)(c >> 2) * 512 + k0 + (c & 3) * 8, buf + c * 8);
  }
}

__device__ __forceinline__ void fused_gemm_dma(
    const unsigned short* __restrict__ W,     // [512][512] bf16, o-major
    const unsigned short (*h_bf)[520],
    unsigned short (*Wl)[16384],
    int tid, int wave, int quad, int l15, f32x4 acc[16]) {
  stage_w32(W, 0, Wl[0], tid);
  int cur = 0;
  for (int k0 = 0; k0 < 512; k0 += 32) {
    __syncthreads();                     // drains DMA into Wl[cur]; orders h_bf
    if (k0 + 32 < 512) stage_w32(W, k0 + 32, Wl[cur ^ 1], tid);
    bf16x8 b0 = *(const bf16x8*)&h_bf[l15][k0 + quad * 8];
    bf16x8 b1 = *(const bf16x8*)&h_bf[16 + l15][k0 + quad * 8];
    const unsigned short* wb = Wl[cur] + (wave * 128 + l15) * 32 + quad * 8;
    #pragma unroll
    for (int oi = 0; oi < 8; ++oi) {
      bf16x8 af = *(const bf16x8*)(wb + oi * 16 * 32);
      acc[oi * 2]     = __builtin_amdgcn_mfma_f32_16x16x32_bf16(af, b0, acc[oi * 2], 0, 0, 0);
      acc[oi * 2 + 1] = __builtin_amdgcn_mfma_f32_16x16x32_bf16(af, b1, acc[oi * 2 + 1], 0, 0, 0);
    }
    cur ^= 1;
  }
  __syncthreads();                       // all h_bf/Wl reads done before caller mutates
}

__global__ __launch_bounds__(256, 1) void inl3_proj_fused(
    const float* __restrict__ h_in,            // [B,S,C] fp32 (attn out)
    const unsigned short* __restrict__ Winl,   // [512][512] bf16
    const float* __restrict__ inl_bias,
    const unsigned short* __restrict__ Wproj,  // [512][512] bf16
    const float* __restrict__ proj_bias,
    const float* __restrict__ x,               // [B,C,S] fp32
    float* __restrict__ out) {                 // [B,C,S] fp32
  __shared__ unsigned short h_bf[32][520];
  __shared__ __align__(16) unsigned short Wl[2][16384];
  __shared__ float bias_lds[2][512];

  int tid = threadIdx.x, wave = tid >> 6, lane = tid & 63;
  int quad = lane >> 4, l15 = lane & 15;
  int bid = blockIdx.x;
  int b = bid >> 5, s0 = (bid & 31) * 32;

  // fp32 h master in registers, acc-layout mirror
  f32x4 h32r[16];
  const float* src = h_in + ((size_t)b * S_ + s0) * 512;
  #pragma unroll
  for (int oi = 0; oi < 8; ++oi) {
    int c = wave * 128 + oi * 16 + quad * 4;
    #pragma unroll
    for (int sj = 0; sj < 2; ++sj) {
      int s = sj * 16 + l15;
      f32x4 v = *(const f32x4*)(src + (size_t)s * 512 + c);
      h32r[oi * 2 + sj] = v;
      ushort4_t hb;
      #pragma unroll
      for (int r = 0; r < 4; ++r) hb[r] = f2bf(v[r]);
      *(ushort4_t*)&h_bf[s][c] = hb;
    }
  }
  if (tid < 128) *(f32x4*)&bias_lds[0][tid * 4] = *(const f32x4*)(inl_bias + tid * 4);
  else *(f32x4*)&bias_lds[1][(tid - 128) * 4] = *(const f32x4*)(proj_bias + (tid - 128) * 4);
  // (no barrier needed here: fused_gemm_dma's loop-top barrier covers it)

  for (int it = 0; it < 3; ++it) {
    f32x4 acc[16];
    #pragma unroll
    for (int t = 0; t < 16; ++t) acc[t] = (f32x4){0.f, 0.f, 0.f, 0.f};
    fused_gemm_dma(Winl, h_bf, Wl, tid, wave, quad, l15, acc);
    // Euler update: thread-local (ownership == acc layout)
    #pragma unroll
    for (int oi = 0; oi < 8; ++oi) {
      int c = wave * 128 + oi * 16 + quad * 4;
      #pragma unroll
      for (int sj = 0; sj < 2; ++sj) {
        int s = sj * 16 + l15;
        f32x4 a = acc[oi * 2 + sj];
        f32x4 h = h32r[oi * 2 + sj];
        ushort4_t hb;
        #pragma unroll
        for (int r = 0; r < 4; ++r) {
          h[r] += DT_STEP * fast_tanh(a[r] + bias_lds[0][c + r]);
          hb[r] = f2bf(h[r]);
        }
        h32r[oi * 2 + sj] = h;
        *(ushort4_t*)&h_bf[s][c] = hb;
      }
    }
    // next gemm's loop-top barrier orders these h_bf writes
  }

  // proj
  f32x4 acc[16];
  #pragma unroll
  for (int t = 0; t < 16; ++t) acc[t] = (f32x4){0.f, 0.f, 0.f, 0.f};
  fused_gemm_dma(Wproj, h_bf, Wl, tid, wave, quad, l15, acc);
  #pragma unroll
  for (int oi = 0; oi < 8; ++oi) {
    int o0 = wave * 128 + oi * 16 + quad * 4;
    #pragma unroll
    for (int sj = 0; sj < 2; ++sj) {
      int sg = s0 + sj * 16 + l15;
      f32x4 a = acc[oi * 2 + sj];
      #pragma unroll
      for (int r = 0; r < 4; ++r) {
        size_t idx = ((size_t)b * C_ + o0 + r) * S_ + sg;
        out[idx] = x[idx] + bias_lds[1][o0 + r] + a[r];
      }
    }
  }
}

extern "C" void kernel_launch(void* const* d_in, const int* in_sizes, int n_in,
                              void* d_out, int out_size, void* d_ws, size_t ws_size,
                              hipStream_t stream) {
  const float* x        = (const float*)d_in[0];
  const float* gn_scale = (const float*)d_in[1];
  const float* gn_bias  = (const float*)d_in[2];
  const float* qkv_w    = (const float*)d_in[3];
  const float* qkv_b    = (const float*)d_in[4];
  const float* proj_w   = (const float*)d_in[5];
  const float* proj_b   = (const float*)d_in[6];
  const float* inl_w    = (const float*)d_in[7];
  const float* inl_b    = (const float*)d_in[8];
  float* out = (float*)d_out;
  float* ws = (float*)d_ws;

  float* A32 = ws;
  float* gpart = ws + 4194304;
  unsigned short* Qt  = (unsigned short*)(ws + 8388608);
  unsigned short* Kt  = (unsigned short*)(ws + 10485760);
  unsigned short* Vt  = (unsigned short*)(ws + 12582912);
  unsigned short* h_t = (unsigned short*)(ws + 14680064);
  unsigned short* qkvw_bf  = (unsigned short*)(ws + 18874368);
  unsigned short* inlw_bf  = qkvw_bf + 786432;
  unsigned short* projw_bf = inlw_bf + 262144;

  cast3_kernel<<<640, 256, 0, stream>>>(qkv_w, inl_w, proj_w, qkvw_bf, inlw_bf, projw_bf);
  gn_stats<<<512, 256, 0, stream>>>(x, gpart);
  gn_apply_t<<<1024, 256, 0, stream>>>(x, gpart, gn_scale, gn_bias, h_t);
  gemm_qkv_mfma<<<dim3(8, 12, 8), 256, 0, stream>>>(qkvw_bf, h_t, qkv_b, Qt, Kt, Vt);
  attn_mfma<<<1024, 256, 0, stream>>>(Qt, Kt, Vt, A32);
  inl3_proj_fused<<<256, 256, 0, stream>>>(A32, inlw_bf, inl_b, projw_bf, proj_b, x, out);
}